// Round 13
// baseline (119.764 us; speedup 1.0000x reference)
//
#include <hip/hip_runtime.h>
#include <cstdint>
#include <cstddef>

#define CIN   256
#define COUT  128

typedef float  f32x4  __attribute__((ext_vector_type(4)));
typedef float  f32x16 __attribute__((ext_vector_type(16)));
typedef __bf16 bf16x8 __attribute__((ext_vector_type(8)));
typedef unsigned int u32x4 __attribute__((ext_vector_type(4)));

// ---------------- workspace layout (bytes) ----------------
// xg: frag-ordered padded x: [b][row 66][cc 16][col 66][16 ci] bf16
#define XG_BYTES   (16ull*66*16*66*16*2)        // 35,684,352
#define WG_OFF     XG_BYTES
#define WG_BYTES   (16ull*16*128*16*2)          // 1,048,576  [tap][cc][co][16ci]
#define SPAD_OFF   (WG_OFF + WG_BYTES)
#define SPAD_BYTES (16ull*66*66*4)              // 278,784    fp32 per-pixel sum(x^2)
#define KSQ_OFF    (SPAD_OFF + SPAD_BYTES)
#define WS_NEEDED  (KSQ_OFF + 512)

__device__ __forceinline__ unsigned short f2bf(float f) {
  unsigned int u = __float_as_uint(f);
  u += 0x7fffu + ((u >> 16) & 1u);              // RNE
  return (unsigned short)(u >> 16);
}

// ---------------- prep: frag-ordered padded x + channel sum ----------
// one block per padded row (b, row); LDS transpose [col][ci] -> [cc][col][16]
__global__ __launch_bounds__(256) void prep_x3(
    const float* __restrict__ x, unsigned short* __restrict__ xg,
    float* __restrict__ spad)
{
  __shared__ __align__(16) unsigned short lw[66*258];    // stride 258 bank-spread
  int blk = blockIdx.x;                          // b*66 + row
  int b = blk / 66, row = blk - b*66;
  int t = threadIdx.x, wave = t >> 6, lane = t & 63;
  bool interior = (row >= 1 && row <= 64);
  int iy = row - 1;

  if (interior) {
    #pragma unroll
    for (int p = 0; p < 16; ++p) {
      int cx = 4*p + wave;                       // input col 0..63
      f32x4 v = *(const f32x4*)(x + (((size_t)b*64 + iy)*64 + cx)*CIN + lane*4);
      ushort4 h; h.x=f2bf(v.x); h.y=f2bf(v.y); h.z=f2bf(v.z); h.w=f2bf(v.w);
      *(ushort4*)&lw[(size_t)(cx+1)*258 + lane*4] = h;
      float s = v.x*v.x + v.y*v.y + v.z*v.z + v.w*v.w;
      #pragma unroll
      for (int off = 32; off > 0; off >>= 1) s += __shfl_down(s, off);
      if (lane == 0) spad[(size_t)blk*66 + cx + 1] = s;
    }
    if (t < 2) spad[(size_t)blk*66 + t*65] = 0.f;
    if (t < 128) {                               // zero pad cols 0 and 65
      int col = (t & 1) * 65, i = t >> 1;        // i: 64 x 4 ci
      *(ushort4*)&lw[(size_t)col*258 + i*4] = (ushort4){0,0,0,0};
    }
  } else {
    if (t < 66) spad[(size_t)blk*66 + t] = 0.f;
  }
  __syncthreads();

  size_t obase = (size_t)blk * 16896;            // shorts: 16cc*66col*16
  #pragma unroll
  for (int k = 0; k < 5; ++k) {
    int un = k*256 + t;                          // unit = cc*66 + col
    if (un < 1056) {
      int cc = un / 66, col = un - cc*66;
      uint4 v0 = {0,0,0,0}, v1 = {0,0,0,0};
      if (interior) {
        v0 = *(uint4*)&lw[(size_t)col*258 + cc*16];
        v1 = *(uint4*)&lw[(size_t)col*258 + cc*16 + 8];
      }
      *(uint4*)(xg + obase + (size_t)un*16) = v0;
      *(uint4*)(xg + obase + (size_t)un*16 + 8) = v1;
    }
  }
}

// ---------------- prep: frag-ordered weights ----------------
// wg[((tap*16 + cc)*128 + co)*16 + k], ci = cc*16 + k
__global__ __launch_bounds__(256) void prep_w3(
    const float* __restrict__ w, unsigned short* __restrict__ wg)
{
  int tap = blockIdx.x;
  int t = threadIdx.x;
  int co = t & 127, kh = t >> 7;                 // kh: which 8-elem half
  #pragma unroll
  for (int cc = 0; cc < 16; ++cc) {
    union { unsigned short u[8]; uint4 v; } hh;
    #pragma unroll
    for (int e = 0; e < 8; ++e)
      hh.u[e] = f2bf(w[((size_t)tap*256 + cc*16 + kh*8 + e)*COUT + co]);
    *(uint4*)(wg + (((size_t)tap*16 + cc)*128 + co)*16 + kh*8) = hh.v;
  }
}

// ---------------- ksq: per-cout kernel squared norm ----------------
__global__ __launch_bounds__(256) void fb_ksq(const float* __restrict__ w,
                                              float* __restrict__ ksq) {
  __shared__ float red[256];
  int co = blockIdx.x, t = threadIdx.x;
  float s = 0.f;
  for (int j = t; j < 4096; j += 256) { float v = w[(size_t)j*COUT + co]; s += v*v; }
  red[t] = s; __syncthreads();
  for (int off = 128; off > 0; off >>= 1) {
    if (t < off) red[t] += red[t + off];
    __syncthreads();
  }
  if (t == 0) ksq[co] = red[0];
}

// ---------------- main fused kernel ----------------
// grid = 1024 (XCD-swizzled): bid -> b = bid>>6, u2 = (bid>>1)&31, py = bid&1
// block = 256 (4 waves): wave = px*2 + coh. Wave tile M=128 (2 output rows
// x 64 v) x N=64 co using 32x32x16 MFMA: 32 MFMAs/cc from 12 A + 8 B frag
// loads (0.625 loads/MFMA -> MFMA pipe > memory pipe for the first time).
// Pure-register K-loop: no LDS, no barriers; asm loads, counted VMW(20).
__global__ __launch_bounds__(256, 1) void yat_main(
    const unsigned short* __restrict__ xg,
    const unsigned short* __restrict__ wg,
    const float* __restrict__ spad,
    const float* __restrict__ ksq,
    const float* __restrict__ bias,
    const float* __restrict__ alpha,
    float* __restrict__ out)
{
  __shared__ float srow[198];

  int orig = blockIdx.x;
  int bid = (orig & 7) * 128 + (orig >> 3);              // XCD-contiguous
  int py = bid & 1, u2 = (bid >> 1) & 31, b = bid >> 6;
  int t = threadIdx.x, wave = t >> 6, lane = t & 63;
  int px = wave >> 1, coh = wave & 1;
  int l31 = lane & 31, hi = lane >> 5;
  int base = 2*u2 + py;                                  // first padded A row

  if (t < 198) {
    int r = t / 66, c = t - r*66;
    srow[t] = spad[((size_t)b*66 + base + r)*66 + c];
  }
  // drain everything (srow loads must not pollute the counted vmcnt FIFO)
  asm volatile("s_waitcnt vmcnt(0) lgkmcnt(0)" ::: "memory");
  __syncthreads();

  // A row pointers: xg[b][base+r][cc=0][col = px + l31][hi*8]
  const char* paB = (const char*)xg
      + ((size_t)(b*66 + base))*33792
      + (size_t)(px + l31)*32 + hi*16;
  const char* pa0 = paB;
  const char* pa1 = paB + 33792;
  const char* pa2 = paB + 67584;
  // B pointers per (a,bb): wg[tap][cc=0][co = coh*64 + l31][hi*8]
  const char* pbB = (const char*)wg + (size_t)(coh*64 + l31)*32 + hi*16;
  const char* pb00 = pbB + (size_t)((py    )*4 + px    )*65536;
  const char* pb01 = pbB + (size_t)((py    )*4 + px + 2)*65536;
  const char* pb10 = pbB + (size_t)((py + 2)*4 + px    )*65536;
  const char* pb11 = pbB + (size_t)((py + 2)*4 + px + 2)*65536;

  f32x16 acc[2][2][2];                                   // [jrow][vh][nt]
  #pragma unroll
  for (int j = 0; j < 2; ++j)
    #pragma unroll
    for (int v = 0; v < 2; ++v)
      #pragma unroll
      for (int n = 0; n < 2; ++n)
        #pragma unroll
        for (int e = 0; e < 16; ++e)
          acc[j][v][n][e] = 0.f;

  u32x4 A0[12], A1[12];                          // [r*4 + vh*2 + bb]
  u32x4 B0[8],  B1[8];                           // [a*4 + bb*2 + nt]

#define SB __builtin_amdgcn_sched_barrier(0)
#define VMW(N) do { asm volatile("s_waitcnt vmcnt(" #N ")" ::: "memory"); SB; } while (0)
#define GLB(dst, base, off)                                                \
  asm volatile("global_load_dwordx4 %0, %1, off offset:%c2"                \
               : "=v"(dst) : "v"(base), "i"(off))

#define ISSUE_A(BK)                                                        \
  {                                                                        \
    GLB(BK[0],  pa0, 0);  GLB(BK[1],  pa0, 32);                            \
    GLB(BK[2],  pa0, 1024); GLB(BK[3],  pa0, 1056);                        \
    GLB(BK[4],  pa1, 0);  GLB(BK[5],  pa1, 32);                            \
    GLB(BK[6],  pa1, 1024); GLB(BK[7],  pa1, 1056);                        \
    GLB(BK[8],  pa2, 0);  GLB(BK[9],  pa2, 32);                            \
    GLB(BK[10], pa2, 1024); GLB(BK[11], pa2, 1056);                        \
  }

#define ISSUE_B(BK)                                                        \
  {                                                                        \
    GLB(BK[0], pb00, 0); GLB(BK[1], pb00, 1024);                           \
    GLB(BK[2], pb01, 0); GLB(BK[3], pb01, 1024);                           \
    GLB(BK[4], pb10, 0); GLB(BK[5], pb10, 1024);                           \
    GLB(BK[6], pb11, 0); GLB(BK[7], pb11, 1024);                           \
  }

#define ADV                                                                \
  { pa0 += 2112; pa1 += 2112; pa2 += 2112;                                 \
    pb00 += 4096; pb01 += 4096; pb10 += 4096; pb11 += 4096; }

#define MFMA32(A_, B_)                                                     \
  {                                                                        \
    _Pragma("unroll")                                                      \
    for (int a = 0; a < 2; ++a)                                            \
      _Pragma("unroll")                                                    \
      for (int bb = 0; bb < 2; ++bb)                                       \
        _Pragma("unroll")                                                  \
        for (int j = 0; j < 2; ++j)                                        \
          _Pragma("unroll")                                                \
          for (int vh = 0; vh < 2; ++vh)                                   \
            _Pragma("unroll")                                              \
            for (int nt = 0; nt < 2; ++nt)                                 \
              acc[j][vh][nt] = __builtin_amdgcn_mfma_f32_32x32x16_bf16(    \
                  __builtin_bit_cast(bf16x8, A_[(j+a)*4 + vh*2 + bb]),     \
                  __builtin_bit_cast(bf16x8, B_[a*4 + bb*2 + nt]),         \
                  acc[j][vh][nt], 0, 0, 0);                                \
  }

#define STEP_FULL(A_, B_) { VMW(20); MFMA32(A_, B_); SB;                   \
                            ISSUE_A(A_); ISSUE_B(B_); SB; ADV; SB; }
#define STEP_T1(A_, B_)   { VMW(20); MFMA32(A_, B_); SB; }
#define STEP_T0(A_, B_)   { VMW(0);  MFMA32(A_, B_); SB; }

  // prologue: banks for cc=0,1
  ISSUE_A(A0); ISSUE_B(B0); SB; ADV; SB;
  ISSUE_A(A1); ISSUE_B(B1); SB; ADV; SB;

  STEP_FULL(A0, B0);   // cc 0  (issues cc 2)
  STEP_FULL(A1, B1);   // cc 1
  STEP_FULL(A0, B0);   // cc 2
  STEP_FULL(A1, B1);   // cc 3
  STEP_FULL(A0, B0);   // cc 4
  STEP_FULL(A1, B1);   // cc 5
  STEP_FULL(A0, B0);   // cc 6
  STEP_FULL(A1, B1);   // cc 7
  STEP_FULL(A0, B0);   // cc 8
  STEP_FULL(A1, B1);   // cc 9
  STEP_FULL(A0, B0);   // cc 10
  STEP_FULL(A1, B1);   // cc 11
  STEP_FULL(A0, B0);   // cc 12
  STEP_FULL(A1, B1);   // cc 13 (issues cc 15)
  STEP_T1(A0, B0);     // cc 14
  STEP_T0(A1, B1);     // cc 15

#undef SB
#undef VMW
#undef GLB
#undef ISSUE_A
#undef ISSUE_B
#undef ADV
#undef MFMA32
#undef STEP_FULL
#undef STEP_T1
#undef STEP_T0

  // ---------------- epilogue ----------------
  float scale = powf(sqrtf(128.f) / log1pf(128.f), alpha[0]);
  float kq[2], bi[2];
  #pragma unroll
  for (int nt = 0; nt < 2; ++nt) {
    int n = coh*64 + nt*32 + l31;
    kq[nt] = ksq[n]; bi[nt] = bias[n];
  }
  #pragma unroll
  for (int j = 0; j < 2; ++j) {
    int oy = 4*u2 + 2*j + py;
    size_t orow = ((size_t)b*128 + oy) * 128 * COUT;
    #pragma unroll
    for (int vh = 0; vh < 2; ++vh) {
      #pragma unroll
      for (int reg = 0; reg < 16; ++reg) {
        int rowid = (reg & 3) + 8*(reg >> 2) + 4*hi;
        int v = vh*32 + rowid;
        float ps = srow[j*66 + v+px] + srow[j*66 + v+px+1]
                 + srow[(j+1)*66 + v+px] + srow[(j+1)*66 + v+px+1];
        #pragma unroll
        for (int nt = 0; nt < 2; ++nt) {
          float dot = acc[j][vh][nt][reg];
          float dist = ps + kq[nt] - 2.f*dot + 1e-5f;
          float y = (dot*dot/dist + bi[nt]) * scale;
          int n = coh*64 + nt*32 + l31;
          out[orow + (size_t)(2*v + px)*COUT + n] = y;
        }
      }
    }
  }
}

// ---------------- fallback (tiny ws): direct fp32 ----------------
__global__ __launch_bounds__(256) void fb_main(
    const float* __restrict__ x, const float* __restrict__ w,
    const float* __restrict__ bias, const float* __restrict__ alpha,
    const float* __restrict__ ksq, float* __restrict__ out)
{
  size_t idx = (size_t)blockIdx.x * 256 + threadIdx.x;
  int co = (int)(idx & 127);
  int ox = (int)((idx >> 7) & 127);
  int oy = (int)((idx >> 14) & 127);
  int b  = (int)(idx >> 21);
  int py = oy & 1, px = ox & 1, u = oy >> 1, v = ox >> 1;
  float dot = 0.f, ps = 0.f;
  for (int a = 0; a < 2; ++a) {
    int iy = u + py + a - 1;
    if (iy < 0 || iy > 63) continue;
    for (int b2 = 0; b2 < 2; ++b2) {
      int ix = v + px + b2 - 1;
      if (ix < 0 || ix > 63) continue;
      const float* xp = x + (((size_t)b*64 + iy)*64 + ix)*CIN;
      const float* wp = w + ((size_t)((py + 2*a)*4 + (px + 2*b2))*CIN)*COUT + co;
      for (int ci = 0; ci < CIN; ++ci) {
        float xv = xp[ci];
        dot += xv * wp[(size_t)ci*COUT];
        ps  += xv * xv;
      }
    }
  }
  float dist = ps + ksq[co] - 2.f*dot + 1e-5f;
  float scale = powf(sqrtf(128.f) / log1pf(128.f), alpha[0]);
  out[idx] = (dot*dot/dist + bias[co]) * scale;
}

// ---------------- launcher ----------------
extern "C" void kernel_launch(void* const* d_in, const int* in_sizes, int n_in,
                              void* d_out, int out_size, void* d_ws, size_t ws_size,
                              hipStream_t stream)
{
  const float* x     = (const float*)d_in[0];
  const float* w     = (const float*)d_in[1];
  const float* bias  = (const float*)d_in[2];
  const float* alpha = (const float*)d_in[3];
  float* out = (float*)d_out;

  if (ws_size < WS_NEEDED) {
    float* ksq = (float*)d_ws;
    fb_ksq<<<128, 256, 0, stream>>>(w, ksq);
    fb_main<<<131072, 256, 0, stream>>>(x, w, bias, alpha, ksq, out);
    return;
  }

  unsigned short* xgp = (unsigned short*)d_ws;
  unsigned short* wgp = (unsigned short*)((char*)d_ws + WG_OFF);
  float* spad = (float*)((char*)d_ws + SPAD_OFF);
  float* ksq  = (float*)((char*)d_ws + KSQ_OFF);

  fb_ksq<<<128, 256, 0, stream>>>(w, ksq);
  prep_x3<<<1056, 256, 0, stream>>>(x, xgp, spad);
  prep_w3<<<16, 256, 0, stream>>>(w, wgp);
  yat_main<<<1024, 256, 0, stream>>>(xgp, wgp, spad, ksq, bias, alpha, out);
}

// Round 14
// 117.442 us; speedup vs baseline: 1.0198x; 1.0198x over previous
//
#include <hip/hip_runtime.h>
#include <cstdint>
#include <cstddef>

#define CIN   256
#define COUT  128

typedef float  f32x4  __attribute__((ext_vector_type(4)));
typedef __bf16 bf16x8 __attribute__((ext_vector_type(8)));
typedef unsigned int u32x4 __attribute__((ext_vector_type(4)));

// ---------------- workspace layout (bytes) ----------------
#define XPAD_BYTES (16ull*66*66*256*2)          // 35,684,352  bf16 padded x
#define WT_OFF     XPAD_BYTES
#define WT_BYTES   (16ull*128*256*2)            // 1,048,576   bf16 w, [tap][co][ci]
#define SPAD_OFF   (WT_OFF + WT_BYTES)
#define SPAD_BYTES (16ull*66*66*4)              // 278,784     fp32 per-pixel sum(x^2)
#define KSQ_OFF    (SPAD_OFF + SPAD_BYTES)
#define WS_NEEDED  (KSQ_OFF + 512)

__device__ __forceinline__ unsigned short f2bf(float f) {
  unsigned int u = __float_as_uint(f);
  u += 0x7fffu + ((u >> 16) & 1u);              // RNE
  return (unsigned short)(u >> 16);
}

__device__ __forceinline__ void async16(const void* lds, const void* g) {
  __builtin_amdgcn_global_load_lds(
      (const __attribute__((address_space(1))) unsigned int*)g,
      (__attribute__((address_space(3))) unsigned int*)lds, 16, 0, 0);
}

// ---------------- prep: pad+convert x, channel sum of x^2 (R5-verified) ----
__global__ __launch_bounds__(256) void prep_x(
    const float* __restrict__ x, unsigned short* __restrict__ xpad,
    float* __restrict__ spad)
{
  int wave = threadIdx.x >> 6, lane = threadIdx.x & 63;
  int p = blockIdx.x * 4 + wave;                 // 0..69695 over [16][66][66]
  int b = p / 4356;
  int rem = p - b * 4356;
  int iyp = rem / 66, ixp = rem - iyp * 66;
  bool interior = (iyp >= 1 && iyp <= 64 && ixp >= 1 && ixp <= 64);
  f32x4 v = {0.f, 0.f, 0.f, 0.f};
  if (interior) {
    const float* src = x + (((size_t)b*64 + (iyp-1))*64 + (ixp-1))*CIN + lane*4;
    v = *(const f32x4*)src;
  }
  ushort4 h;
  h.x = f2bf(v.x); h.y = f2bf(v.y); h.z = f2bf(v.z); h.w = f2bf(v.w);
  *(ushort4*)(xpad + (size_t)p*CIN + lane*4) = h;
  float s = v.x*v.x + v.y*v.y + v.z*v.z + v.w*v.w;
  #pragma unroll
  for (int off = 32; off > 0; off >>= 1) s += __shfl_down(s, off);
  if (lane == 0) spad[p] = s;
}

// ---------------- prep: wt [tap][co][ci] + ksq (R5-verified) ----------------
__global__ __launch_bounds__(256) void prep_w(
    const float* __restrict__ w, unsigned short* __restrict__ wt,
    float* __restrict__ ksq)
{
  __shared__ __align__(16) unsigned short lw[32*128];
  __shared__ f32x4 red[256];
  int t = threadIdx.x;
  int tap = blockIdx.x >> 3;
  int ci0 = (blockIdx.x & 7) * 32;
  f32x4 sq = {0.f, 0.f, 0.f, 0.f};
  int co4 = (t & 31) * 4;
  #pragma unroll
  for (int i = 0; i < 4; ++i) {
    int ci = (t >> 5) + i*8;
    const float* src = w + ((size_t)(tap*256 + ci0 + ci))*COUT + co4;
    f32x4 v = *(const f32x4*)src;
    sq.x += v.x*v.x; sq.y += v.y*v.y; sq.z += v.z*v.z; sq.w += v.w*v.w;
    ushort4 h; h.x = f2bf(v.x); h.y = f2bf(v.y); h.z = f2bf(v.z); h.w = f2bf(v.w);
    *(ushort4*)&lw[ci*128 + co4] = h;
  }
  red[t] = sq;
  __syncthreads();
  if (t < 32) {
    f32x4 tot = red[t];
    #pragma unroll
    for (int j = 1; j < 8; ++j) {
      f32x4 o = red[t + 32*j];
      tot.x += o.x; tot.y += o.y; tot.z += o.z; tot.w += o.w;
    }
    atomicAdd(ksq + t*4 + 0, tot.x);
    atomicAdd(ksq + t*4 + 1, tot.y);
    atomicAdd(ksq + t*4 + 2, tot.z);
    atomicAdd(ksq + t*4 + 3, tot.w);
  }
  int co = t >> 1, h16 = (t & 1) * 16;
  union { unsigned short u[16]; uint4 q[2]; } tmp;
  #pragma unroll
  for (int i = 0; i < 16; ++i) tmp.u[i] = lw[(h16 + i)*128 + co];
  uint4* dst = (uint4*)(wt + ((size_t)tap*128 + co)*CIN + ci0 + h16);
  dst[0] = tmp.q[0]; dst[1] = tmp.q[1];
}

// ---------------- main fused kernel (m201-style phased LDS GEMM) ----------
// grid = 1024: bid -> px=bid&1, py=(bid>>1)&1, u4=(bid>>2)&15, b=bid>>6
// block = 512 (8 waves): wave = coh*4 + rp. Wave tile: u-row rp (64 v) x 64 co.
// 16 tap-chunks: t -> s=t>>2 (ci-64), a=(t>>1)&1, bb=t&1.
// A: [5 rows][col][q] per ci-64, depth-2 LDS (reused by 4 tap-chunks).
// B: [co][q] per (tap, ci-64), depth-3 LDS. Both XOR-swizzled (q ^= col/co &7)
// on SOURCE at stage and on ds_read addr (involution). One barrier per chunk,
// counted vmcnt pattern [2,8,8,2], never 0 until the tail.
__global__ __launch_bounds__(512, 1) void yat_main(
    const unsigned short* __restrict__ xpad,
    const unsigned short* __restrict__ wt,
    const float* __restrict__ spad,
    const float* __restrict__ ksq,
    const float* __restrict__ bias,
    const float* __restrict__ alpha,
    float* __restrict__ out)
{
  __shared__ __align__(16) unsigned short xsA[2][23040];  // 2 x 46080 B (5 rows x 9216)
  __shared__ __align__(16) unsigned short xsB[3][8192];   // 3 x 16384 B
  __shared__ __align__(16) unsigned short scrap[512];     // dummy gload sink
  __shared__ float srow[330];

  int orig = blockIdx.x;
  int bid = (orig & 7) * 128 + (orig >> 3);               // XCD-contiguous
  int px = bid & 1, py = (bid >> 1) & 1, u4 = (bid >> 2) & 15, b = bid >> 6;
  int t = threadIdx.x, wave = t >> 6, lane = t & 63;
  int rp = wave & 3, coh = wave >> 2;
  int l15 = lane & 15, l4 = lane >> 4;
  int bRow0 = u4*4 + py;

  if (t < 330) {
    int r = t / 66, c = t - r*66;
    srow[t] = spad[((size_t)b*66 + bRow0 + r)*66 + c];
  }
  asm volatile("s_waitcnt vmcnt(0) lgkmcnt(0)" ::: "memory");
  __syncthreads();

  // ---- A staging slots: 45 wave-instrs (5 rows x 9 col-blocks) over 8 waves
  //      x 6 rounds; invalid slots -> scrap (uniform 6 vmem per wave).
  const char* srcA[6];
  unsigned short* dstA[6];
  int mulA[6];
  #pragma unroll
  for (int r = 0; r < 6; ++r) {
    int k = r*8 + wave;
    int kk = (k < 45) ? k : 44;
    int row = kk / 9, cb = kk - row*9;
    int col = cb*8 + (lane >> 3); if (col > 65) col = 65;
    int qs = (lane & 7) ^ (col & 7);
    srcA[r] = (const char*)xpad
            + (((size_t)(b*66 + bRow0 + row))*66 + col)*512 + qs*16;
    dstA[r] = (k < 45) ? (&xsA[0][0] + row*4608 + cb*512) : &scrap[0];
    mulA[r] = (k < 45) ? 23040 : 0;                       // shorts
  }
  // ---- B staging slots: 16 wave-instrs over 8 waves x 2 rounds
  const char* srcB[2][4];
  unsigned short* dstB[2];
  #pragma unroll
  for (int r = 0; r < 2; ++r) {
    int k = r*8 + wave;
    int co = k*8 + (lane >> 3);
    int qs = (lane & 7) ^ (co & 7);
    dstB[r] = &xsB[0][0] + k*512;
    #pragma unroll
    for (int ab = 0; ab < 4; ++ab) {
      int tap = (py + 2*(ab >> 1))*4 + px + 2*(ab & 1);
      srcB[r][ab] = (const char*)wt + (size_t)tap*65536 + (size_t)co*512 + qs*16;
    }
  }

  // ---- per-lane ds_read bases (swizzled) ----
  unsigned aB0 = (unsigned)(unsigned long long)(&xsA[0][0]) + (unsigned)(rp*9216);
  unsigned abA[2][2];                                     // [bb][sub]
  #pragma unroll
  for (int bb = 0; bb < 2; ++bb) {
    int c7 = (l15 + px + bb) & 7;
    #pragma unroll
    for (int sub = 0; sub < 2; ++sub)
      abA[bb][sub] = aB0 + (l15 + px + bb)*128 + (((sub*4 + l4) ^ c7) << 4);
  }
  unsigned bB0 = (unsigned)(unsigned long long)(&xsB[0][0]) + (coh*64 + l15)*128;
  unsigned abB[2];
  #pragma unroll
  for (int sub = 0; sub < 2; ++sub)
    abB[sub] = bB0 + (((sub*4 + l4) ^ (l15 & 7)) << 4);

  f32x4 acc[4][4];
  #pragma unroll
  for (int i = 0; i < 4; ++i)
    #pragma unroll
    for (int j = 0; j < 4; ++j)
      acc[i][j] = (f32x4){0.f, 0.f, 0.f, 0.f};

#define SB  __builtin_amdgcn_sched_barrier(0)
#define BAR __builtin_amdgcn_s_barrier()
#define VMW(N) do { asm volatile("s_waitcnt vmcnt(" #N ")" ::: "memory"); SB; } while (0)
#define LGKW(N) do { asm volatile("s_waitcnt lgkmcnt(" #N ")" ::: "memory"); SB; } while (0)
#define DSR(dst, addr, off)                                                \
  asm volatile("ds_read_b128 %0, %1 offset:%c2"                            \
               : "=v"(dst) : "v"(addr), "i"(off))

#define STAGE_A(BUF, S) {                                                  \
    async16(dstA[0] + (BUF)*mulA[0], srcA[0] + (S)*128);                   \
    async16(dstA[1] + (BUF)*mulA[1], srcA[1] + (S)*128);                   \
    async16(dstA[2] + (BUF)*mulA[2], srcA[2] + (S)*128);                   \
    async16(dstA[3] + (BUF)*mulA[3], srcA[3] + (S)*128);                   \
    async16(dstA[4] + (BUF)*mulA[4], srcA[4] + (S)*128);                   \
    async16(dstA[5] + (BUF)*mulA[5], srcA[5] + (S)*128); }

#define STAGE_B(TT, BI) {                                                  \
    async16(dstB[0] + (BI)*8192, srcB[0][(TT)&3] + ((TT)>>2)*128);         \
    async16(dstB[1] + (BI)*8192, srcB[1][(TT)&3] + ((TT)>>2)*128); }

#define MFMA16(A_, B_)                                                     \
  { _Pragma("unroll")                                                      \
    for (int mt = 0; mt < 4; ++mt)                                         \
      _Pragma("unroll")                                                    \
      for (int nt = 0; nt < 4; ++nt)                                       \
        acc[mt][nt] = __builtin_amdgcn_mfma_f32_16x16x32_bf16(             \
            __builtin_bit_cast(bf16x8, A_[mt]),                            \
            __builtin_bit_cast(bf16x8, B_[nt]),                            \
            acc[mt][nt], 0, 0, 0); }

#define COMPUTE(BUFA, AA, BB, BI) {                                        \
    u32x4 Af0[4], Bf0[4], Af1[4], Bf1[4];                                  \
    DSR(Af0[0], abA[BB][0], (BUFA)*46080 + (AA)*9216 + 0);                 \
    DSR(Af0[1], abA[BB][0], (BUFA)*46080 + (AA)*9216 + 2048);              \
    DSR(Af0[2], abA[BB][0], (BUFA)*46080 + (AA)*9216 + 4096);              \
    DSR(Af0[3], abA[BB][0], (BUFA)*46080 + (AA)*9216 + 6144);              \
    DSR(Bf0[0], abB[0], (BI)*16384 + 0);                                   \
    DSR(Bf0[1], abB[0], (BI)*16384 + 2048);                                \
    DSR(Bf0[2], abB[0], (BI)*16384 + 4096);                                \
    DSR(Bf0[3], abB[0], (BI)*16384 + 6144);                                \
    DSR(Af1[0], abA[BB][1], (BUFA)*46080 + (AA)*9216 + 0);                 \
    DSR(Af1[1], abA[BB][1], (BUFA)*46080 + (AA)*9216 + 2048);              \
    DSR(Af1[2], abA[BB][1], (BUFA)*46080 + (AA)*9216 + 4096);              \
    DSR(Af1[3], abA[BB][1], (BUFA)*46080 + (AA)*9216 + 6144);              \
    DSR(Bf1[0], abB[1], (BI)*16384 + 0);                                   \
    DSR(Bf1[1], abB[1], (BI)*16384 + 2048);                                \
    DSR(Bf1[2], abB[1], (BI)*16384 + 4096);                                \
    DSR(Bf1[3], abB[1], (BI)*16384 + 6144);                                \
    LGKW(8);                                                               \
    __builtin_amdgcn_s_setprio(1); MFMA16(Af0, Bf0);                       \
    __builtin_amdgcn_s_setprio(0);                                         \
    LGKW(0);                                                               \
    __builtin_amdgcn_s_setprio(1); MFMA16(Af1, Bf1);                       \
    __builtin_amdgcn_s_setprio(0); SB; }

  SB;
  // prologue FIFO: B(0)x2, A(0)x6, B(1)x2
  STAGE_B(0, 0);
  STAGE_A(0, 0);
  STAGE_B(1, 1);
  SB;
  VMW(2); BAR; STAGE_B(2, 2);  STAGE_A(1, 1); SB; COMPUTE(0, 0, 0, 0);  // t=0
  VMW(8); BAR; STAGE_B(3, 0);  SB;               COMPUTE(0, 0, 1, 1);   // t=1
  VMW(8); BAR; STAGE_B(4, 1);  SB;               COMPUTE(0, 1, 0, 2);   // t=2
  VMW(2); BAR; STAGE_B(5, 2);  SB;               COMPUTE(0, 1, 1, 0);   // t=3
  VMW(2); BAR; STAGE_B(6, 0);  STAGE_A(0, 2); SB; COMPUTE(1, 0, 0, 1);  // t=4
  VMW(8); BAR; STAGE_B(7, 1);  SB;               COMPUTE(1, 0, 1, 2);   // t=5
  VMW(8); BAR; STAGE_B(8, 2);  SB;               COMPUTE(1, 1, 0, 0);   // t=6
  VMW(2); BAR; STAGE_B(9, 0);  SB;               COMPUTE(1, 1, 1, 1);   // t=7
  VMW(2); BAR; STAGE_B(10, 1); STAGE_A(1, 3); SB; COMPUTE(0, 0, 0, 2);  // t=8
  VMW(8); BAR; STAGE_B(11, 2); SB;               COMPUTE(0, 0, 1, 0);   // t=9
  VMW(8); BAR; STAGE_B(12, 0); SB;               COMPUTE(0, 1, 0, 1);   // t=10
  VMW(2); BAR; STAGE_B(13, 1); SB;               COMPUTE(0, 1, 1, 2);   // t=11
  VMW(2); BAR; STAGE_B(14, 2); SB;               COMPUTE(1, 0, 0, 0);   // t=12
  VMW(2); BAR; STAGE_B(15, 0); SB;               COMPUTE(1, 0, 1, 1);   // t=13
  VMW(2); BAR;                                   COMPUTE(1, 1, 0, 2);   // t=14
  VMW(0); BAR;                                   COMPUTE(1, 1, 1, 0);   // t=15

#undef SB
#undef BAR
#undef VMW
#undef LGKW
#undef DSR
#undef STAGE_A
#undef STAGE_B
#undef MFMA16
#undef COMPUTE

  // ---------------- epilogue ----------------
  float scale = powf(sqrtf(128.f) / log1pf(128.f), alpha[0]);
  float kq[4], bi[4];
  #pragma unroll
  for (int nt = 0; nt < 4; ++nt) {
    int n = coh*64 + nt*16 + l15;
    kq[nt] = ksq[n]; bi[nt] = bias[n];
  }
  int oy = 2*(u4*4 + rp) + py;
  size_t orow = ((size_t)b*128 + oy) * 128 * COUT;
  #pragma unroll
  for (int mt = 0; mt < 4; ++mt) {
    #pragma unroll
    for (int r = 0; r < 4; ++r) {
      int v = mt*16 + l4*4 + r;
      int vpx = v + px;
      float ps = srow[rp*66 + vpx] + srow[rp*66 + vpx + 1]
               + srow[rp*66 + 66 + vpx] + srow[rp*66 + 66 + vpx + 1];
      #pragma unroll
      for (int nt = 0; nt < 4; ++nt) {
        float dot = acc[mt][nt][r];
        float dist = ps + kq[nt] - 2.f*dot + 1e-5f;
        float y = (dot*dot/dist + bi[nt]) * scale;
        int n = coh*64 + nt*16 + l15;
        out[orow + (size_t)(2*v + px)*COUT + n] = y;
      }
    }
  }
}

// ---------------- fallback (tiny ws): direct fp32 ----------------
__global__ __launch_bounds__(256) void fb_ksq(const float* __restrict__ w,
                                              float* __restrict__ ksq) {
  __shared__ float red[256];
  int co = blockIdx.x, t = threadIdx.x;
  float s = 0.f;
  for (int j = t; j < 4096; j += 256) { float v = w[(size_t)j*COUT + co]; s += v*v; }
  red[t] = s; __syncthreads();
  for (int off = 128; off > 0; off >>= 1) {
    if (t < off) red[t] += red[t + off];
    __syncthreads();
  }
  if (t == 0) ksq[co] = red[0];
}

__global__ __launch_bounds__(256) void fb_main(
    const float* __restrict__ x, const float* __restrict__ w,
    const float* __restrict__ bias, const float* __restrict__ alpha,
    const float* __restrict__ ksq, float* __restrict__ out)
{
  size_t idx = (size_t)blockIdx.x * 256 + threadIdx.x;
  int co = (int)(idx & 127);
  int ox = (int)((idx >> 7) & 127);
  int oy = (int)((idx >> 14) & 127);
  int b  = (int)(idx >> 21);
  int py = oy & 1, px = ox & 1, u = oy >> 1, v = ox >> 1;
  float dot = 0.f, ps = 0.f;
  for (int a = 0; a < 2; ++a) {
    int iy = u + py + a - 1;
    if (iy < 0 || iy > 63) continue;
    for (int b2 = 0; b2 < 2; ++b2) {
      int ix = v + px + b2 - 1;
      if (ix < 0 || ix > 63) continue;
      const float* xp = x + (((size_t)b*64 + iy)*64 + ix)*CIN;
      const float* wp = w + ((size_t)((py + 2*a)*4 + (px + 2*b2))*CIN)*COUT + co;
      for (int ci = 0; ci < CIN; ++ci) {
        float xv = xp[ci];
        dot += xv * wp[(size_t)ci*COUT];
        ps  += xv * xv;
      }
    }
  }
  float dist = ps + ksq[co] - 2.f*dot + 1e-5f;
  float scale = powf(sqrtf(128.f) / log1pf(128.f), alpha[0]);
  out[idx] = (dot*dot/dist + bias[co]) * scale;
}

// ---------------- launcher ----------------
extern "C" void kernel_launch(void* const* d_in, const int* in_sizes, int n_in,
                              void* d_out, int out_size, void* d_ws, size_t ws_size,
                              hipStream_t stream)
{
  const float* x     = (const float*)d_in[0];
  const float* w     = (const float*)d_in[1];
  const float* bias  = (const float*)d_in[2];
  const float* alpha = (const float*)d_in[3];
  float* out = (float*)d_out;

  if (ws_size < WS_NEEDED) {
    float* ksq = (float*)d_ws;
    fb_ksq<<<128, 256, 0, stream>>>(w, ksq);
    fb_main<<<131072, 256, 0, stream>>>(x, w, bias, alpha, ksq, out);
    return;
  }

  unsigned short* xpad = (unsigned short*)d_ws;
  unsigned short* wtp  = (unsigned short*)((char*)d_ws + WT_OFF);
  float* spad = (float*)((char*)d_ws + SPAD_OFF);
  float* ksq  = (float*)((char*)d_ws + KSQ_OFF);

  hipMemsetAsync(ksq, 0, 512, stream);
  prep_x<<<17424, 256, 0, stream>>>(x, xpad, spad);
  prep_w<<<128, 256, 0, stream>>>(w, wtp, ksq);
  yat_main<<<1024, 512, 0, stream>>>(xpad, wtp, spad, ksq, bias, alpha, out);
}

// Round 15
// 117.394 us; speedup vs baseline: 1.0202x; 1.0004x over previous
//
#include <hip/hip_runtime.h>
#include <cstdint>
#include <cstddef>

#define CIN   256
#define COUT  128

typedef float  f32x4  __attribute__((ext_vector_type(4)));
typedef __bf16 bf16x8 __attribute__((ext_vector_type(8)));
typedef unsigned int u32x4 __attribute__((ext_vector_type(4)));

// ---------------- workspace layout (bytes) ----------------
#define XPAD_BYTES (16ull*66*66*256*2)          // 35,684,352  bf16 padded x
#define WT_OFF     XPAD_BYTES
#define WT_BYTES   (16ull*128*256*2)            // 1,048,576   bf16 w, [tap][co][ci]
#define SPAD_OFF   (WT_OFF + WT_BYTES)
#define SPAD_BYTES (16ull*66*66*4)              // 278,784     fp32 per-pixel sum(x^2)
#define KSQ_OFF    (SPAD_OFF + SPAD_BYTES)
#define WS_NEEDED  (KSQ_OFF + 512)

__device__ __forceinline__ unsigned short f2bf(float f) {
  unsigned int u = __float_as_uint(f);
  u += 0x7fffu + ((u >> 16) & 1u);              // RNE
  return (unsigned short)(u >> 16);
}

__device__ __forceinline__ void async16(const void* lds, const void* g) {
  __builtin_amdgcn_global_load_lds(
      (const __attribute__((address_space(1))) unsigned int*)g,
      (__attribute__((address_space(3))) unsigned int*)lds, 16, 0, 0);
}

// ---------------- prep: pad+convert x, channel sum of x^2 (R5-verified) ----
__global__ __launch_bounds__(256) void prep_x(
    const float* __restrict__ x, unsigned short* __restrict__ xpad,
    float* __restrict__ spad)
{
  int wave = threadIdx.x >> 6, lane = threadIdx.x & 63;
  int p = blockIdx.x * 4 + wave;                 // 0..69695 over [16][66][66]
  int b = p / 4356;
  int rem = p - b * 4356;
  int iyp = rem / 66, ixp = rem - iyp * 66;
  bool interior = (iyp >= 1 && iyp <= 64 && ixp >= 1 && ixp <= 64);
  f32x4 v = {0.f, 0.f, 0.f, 0.f};
  if (interior) {
    const float* src = x + (((size_t)b*64 + (iyp-1))*64 + (ixp-1))*CIN + lane*4;
    v = *(const f32x4*)src;
  }
  ushort4 h;
  h.x = f2bf(v.x); h.y = f2bf(v.y); h.z = f2bf(v.z); h.w = f2bf(v.w);
  *(ushort4*)(xpad + (size_t)p*CIN + lane*4) = h;
  float s = v.x*v.x + v.y*v.y + v.z*v.z + v.w*v.w;
  #pragma unroll
  for (int off = 32; off > 0; off >>= 1) s += __shfl_down(s, off);
  if (lane == 0) spad[p] = s;
}

// ---------------- prep: wt [tap][co][ci] + ksq (R5-verified) ----------------
__global__ __launch_bounds__(256) void prep_w(
    const float* __restrict__ w, unsigned short* __restrict__ wt,
    float* __restrict__ ksq)
{
  __shared__ __align__(16) unsigned short lw[32*128];
  __shared__ f32x4 red[256];
  int t = threadIdx.x;
  int tap = blockIdx.x >> 3;
  int ci0 = (blockIdx.x & 7) * 32;
  f32x4 sq = {0.f, 0.f, 0.f, 0.f};
  int co4 = (t & 31) * 4;
  #pragma unroll
  for (int i = 0; i < 4; ++i) {
    int ci = (t >> 5) + i*8;
    const float* src = w + ((size_t)(tap*256 + ci0 + ci))*COUT + co4;
    f32x4 v = *(const f32x4*)src;
    sq.x += v.x*v.x; sq.y += v.y*v.y; sq.z += v.z*v.z; sq.w += v.w*v.w;
    ushort4 h; h.x = f2bf(v.x); h.y = f2bf(v.y); h.z = f2bf(v.z); h.w = f2bf(v.w);
    *(ushort4*)&lw[ci*128 + co4] = h;
  }
  red[t] = sq;
  __syncthreads();
  if (t < 32) {
    f32x4 tot = red[t];
    #pragma unroll
    for (int j = 1; j < 8; ++j) {
      f32x4 o = red[t + 32*j];
      tot.x += o.x; tot.y += o.y; tot.z += o.z; tot.w += o.w;
    }
    atomicAdd(ksq + t*4 + 0, tot.x);
    atomicAdd(ksq + t*4 + 1, tot.y);
    atomicAdd(ksq + t*4 + 2, tot.z);
    atomicAdd(ksq + t*4 + 3, tot.w);
  }
  int co = t >> 1, h16 = (t & 1) * 16;
  union { unsigned short u[16]; uint4 q[2]; } tmp;
  #pragma unroll
  for (int i = 0; i < 16; ++i) tmp.u[i] = lw[(h16 + i)*128 + co];
  uint4* dst = (uint4*)(wt + ((size_t)tap*128 + co)*CIN + ci0 + h16);
  dst[0] = tmp.q[0]; dst[1] = tmp.q[1];
}

// ---------------- main fused kernel (R14 + pipelined reads/MFMA overlap) ---
// grid = 1024: bid -> px=bid&1, py=(bid>>1)&1, u4=(bid>>2)&15, b=bid>>6
// block = 512 (8 waves): wave = coh*4 + rp. Wave tile: u-row rp (64 v) x 64 co.
// Per chunk: two 8-read/16-MFMA phases, ping-pong reg sets; each phase's reads
// issued one phase EARLY (counted lgkmcnt(8)) so the LDS pipe fills while the
// MFMA pipe drains the previous phase. Staging FIFO identical to R14.
__global__ __launch_bounds__(512, 1) void yat_main(
    const unsigned short* __restrict__ xpad,
    const unsigned short* __restrict__ wt,
    const float* __restrict__ spad,
    const float* __restrict__ ksq,
    const float* __restrict__ bias,
    const float* __restrict__ alpha,
    float* __restrict__ out)
{
  __shared__ __align__(16) unsigned short xsA[2][23040];  // 2 x 46080 B
  __shared__ __align__(16) unsigned short xsB[3][8192];   // 3 x 16384 B
  __shared__ __align__(16) unsigned short scrap[512];
  __shared__ float srow[330];

  int orig = blockIdx.x;
  int bid = (orig & 7) * 128 + (orig >> 3);               // XCD-contiguous
  int px = bid & 1, py = (bid >> 1) & 1, u4 = (bid >> 2) & 15, b = bid >> 6;
  int t = threadIdx.x, wave = t >> 6, lane = t & 63;
  int rp = wave & 3, coh = wave >> 2;
  int l15 = lane & 15, l4 = lane >> 4;
  int bRow0 = u4*4 + py;

  if (t < 330) {
    int r = t / 66, c = t - r*66;
    srow[t] = spad[((size_t)b*66 + bRow0 + r)*66 + c];
  }
  asm volatile("s_waitcnt vmcnt(0) lgkmcnt(0)" ::: "memory");
  __syncthreads();

  // ---- A staging slots (45 over 8 waves x 6 rounds; overflow -> scrap) ----
  const char* srcA[6];
  unsigned short* dstA[6];
  int mulA[6];
  #pragma unroll
  for (int r = 0; r < 6; ++r) {
    int k = r*8 + wave;
    int kk = (k < 45) ? k : 44;
    int row = kk / 9, cb = kk - row*9;
    int col = cb*8 + (lane >> 3); if (col > 65) col = 65;
    int qs = (lane & 7) ^ (col & 7);
    srcA[r] = (const char*)xpad
            + (((size_t)(b*66 + bRow0 + row))*66 + col)*512 + qs*16;
    dstA[r] = (k < 45) ? (&xsA[0][0] + row*4608 + cb*512) : &scrap[0];
    mulA[r] = (k < 45) ? 23040 : 0;
  }
  // ---- B staging slots (16 over 8 waves x 2 rounds) ----
  const char* srcB[2][4];
  unsigned short* dstB[2];
  #pragma unroll
  for (int r = 0; r < 2; ++r) {
    int k = r*8 + wave;
    int co = k*8 + (lane >> 3);
    int qs = (lane & 7) ^ (co & 7);
    dstB[r] = &xsB[0][0] + k*512;
    #pragma unroll
    for (int ab = 0; ab < 4; ++ab) {
      int tap = (py + 2*(ab >> 1))*4 + px + 2*(ab & 1);
      srcB[r][ab] = (const char*)wt + (size_t)tap*65536 + (size_t)co*512 + qs*16;
    }
  }

  // ---- per-lane ds_read bases (swizzled) ----
  unsigned aB0 = (unsigned)(unsigned long long)(&xsA[0][0]) + (unsigned)(rp*9216);
  unsigned abA[2][2];
  #pragma unroll
  for (int bb = 0; bb < 2; ++bb) {
    int c7 = (l15 + px + bb) & 7;
    #pragma unroll
    for (int sub = 0; sub < 2; ++sub)
      abA[bb][sub] = aB0 + (l15 + px + bb)*128 + (((sub*4 + l4) ^ c7) << 4);
  }
  unsigned bB0 = (unsigned)(unsigned long long)(&xsB[0][0]) + (coh*64 + l15)*128;
  unsigned abB[2];
  #pragma unroll
  for (int sub = 0; sub < 2; ++sub)
    abB[sub] = bB0 + (((sub*4 + l4) ^ (l15 & 7)) << 4);

  f32x4 acc[4][4];
  #pragma unroll
  for (int i = 0; i < 4; ++i)
    #pragma unroll
    for (int j = 0; j < 4; ++j)
      acc[i][j] = (f32x4){0.f, 0.f, 0.f, 0.f};

  u32x4 Xa[4], Xb[4], Ya[4], Yb[4];              // ping-pong operand sets

#define SB  __builtin_amdgcn_sched_barrier(0)
#define BAR __builtin_amdgcn_s_barrier()
#define VMW(N) do { asm volatile("s_waitcnt vmcnt(" #N ")" ::: "memory"); SB; } while (0)
#define LGK(N) do { asm volatile("s_waitcnt lgkmcnt(" #N ")" ::: "memory"); SB; } while (0)
#define DSR(dst, addr, off)                                                \
  asm volatile("ds_read_b128 %0, %1 offset:%c2"                            \
               : "=v"(dst) : "v"(addr), "i"(off))

#define STAGE_A(BUF, S) {                                                  \
    async16(dstA[0] + (BUF)*mulA[0], srcA[0] + (S)*128);                   \
    async16(dstA[1] + (BUF)*mulA[1], srcA[1] + (S)*128);                   \
    async16(dstA[2] + (BUF)*mulA[2], srcA[2] + (S)*128);                   \
    async16(dstA[3] + (BUF)*mulA[3], srcA[3] + (S)*128);                   \
    async16(dstA[4] + (BUF)*mulA[4], srcA[4] + (S)*128);                   \
    async16(dstA[5] + (BUF)*mulA[5], srcA[5] + (S)*128); }

#define STAGE_B(TT, BI) {                                                  \
    async16(dstB[0] + (BI)*8192, srcB[0][(TT)&3] + ((TT)>>2)*128);         \
    async16(dstB[1] + (BI)*8192, srcB[1][(TT)&3] + ((TT)>>2)*128); }

  // 8 ds_reads: A frags (4) + B frags (4) for phase SUB of chunk (BUFA,AA,BB,BI)
#define READS(RA, RB_, BUFA, AA, BB, SUB, BI) {                            \
    DSR(RA[0], abA[BB][SUB], (BUFA)*46080 + (AA)*9216 + 0);                \
    DSR(RA[1], abA[BB][SUB], (BUFA)*46080 + (AA)*9216 + 2048);             \
    DSR(RA[2], abA[BB][SUB], (BUFA)*46080 + (AA)*9216 + 4096);             \
    DSR(RA[3], abA[BB][SUB], (BUFA)*46080 + (AA)*9216 + 6144);             \
    DSR(RB_[0], abB[SUB], (BI)*16384 + 0);                                 \
    DSR(RB_[1], abB[SUB], (BI)*16384 + 2048);                              \
    DSR(RB_[2], abB[SUB], (BI)*16384 + 4096);                              \
    DSR(RB_[3], abB[SUB], (BI)*16384 + 6144); }

#define MFMA16(A_, B_)                                                     \
  { _Pragma("unroll")                                                      \
    for (int mt = 0; mt < 4; ++mt)                                         \
      _Pragma("unroll")                                                    \
      for (int nt = 0; nt < 4; ++nt)                                       \
        acc[mt][nt] = __builtin_amdgcn_mfma_f32_16x16x32_bf16(             \
            __builtin_bit_cast(bf16x8, A_[mt]),                            \
            __builtin_bit_cast(bf16x8, B_[nt]),                            \
            acc[mt][nt], 0, 0, 0); }

#define PHB(A_, B_) { LGK(8); __builtin_amdgcn_s_setprio(1); MFMA16(A_, B_); \
                      __builtin_amdgcn_s_setprio(0); SB; }
#define PHF(A_, B_) { __builtin_amdgcn_s_setprio(1); MFMA16(A_, B_);       \
                      __builtin_amdgcn_s_setprio(0); SB; }

  SB;
  // ---- prologue: B(0), A(s0), B(1), B(2); retire B0+A0; reads chunk0 p0 ----
  STAGE_B(0, 0);
  STAGE_A(0, 0);
  STAGE_B(1, 1);
  STAGE_B(2, 2);
  SB;
  VMW(4); BAR; SB;
  READS(Xa, Xb, 0,0,0, 0, 0); SB;

  // ---- chunk 0 (0,0,0,0) -> next (0,0,1,1), n=2, D: B(3)+A(s1) ----
  READS(Ya, Yb, 0,0,0, 1, 0); SB;
  PHB(Xa, Xb);
  LGK(0); VMW(2); BAR; SB;
  STAGE_B(3, 0); STAGE_A(1, 1); SB;
  READS(Xa, Xb, 0,0,1, 0, 1); SB;
  PHF(Ya, Yb);
  // ---- chunk 1 (0,0,1,1) -> (0,1,0,2), n=8, D: B(4) ----
  READS(Ya, Yb, 0,0,1, 1, 1); SB;
  PHB(Xa, Xb);
  LGK(0); VMW(8); BAR; SB;
  STAGE_B(4, 1); SB;
  READS(Xa, Xb, 0,1,0, 0, 2); SB;
  PHF(Ya, Yb);
  // ---- chunk 2 (0,1,0,2) -> (0,1,1,0), n=2, D: B(5) ----
  READS(Ya, Yb, 0,1,0, 1, 2); SB;
  PHB(Xa, Xb);
  LGK(0); VMW(2); BAR; SB;
  STAGE_B(5, 2); SB;
  READS(Xa, Xb, 0,1,1, 0, 0); SB;
  PHF(Ya, Yb);
  // ---- chunk 3 (0,1,1,0) -> (1,0,0,1), n=2, D: B(6) ----
  READS(Ya, Yb, 0,1,1, 1, 0); SB;
  PHB(Xa, Xb);
  LGK(0); VMW(2); BAR; SB;
  STAGE_B(6, 0); SB;
  READS(Xa, Xb, 1,0,0, 0, 1); SB;
  PHF(Ya, Yb);
  // ---- chunk 4 (1,0,0,1) -> (1,0,1,2), n=2, D: B(7)+A(s2) ----
  READS(Ya, Yb, 1,0,0, 1, 1); SB;
  PHB(Xa, Xb);
  LGK(0); VMW(2); BAR; SB;
  STAGE_B(7, 1); STAGE_A(0, 2); SB;
  READS(Xa, Xb, 1,0,1, 0, 2); SB;
  PHF(Ya, Yb);
  // ---- chunk 5 (1,0,1,2) -> (1,1,0,0), n=8, D: B(8) ----
  READS(Ya, Yb, 1,0,1, 1, 2); SB;
  PHB(Xa, Xb);
  LGK(0); VMW(8); BAR; SB;
  STAGE_B(8, 2); SB;
  READS(Xa, Xb, 1,1,0, 0, 0); SB;
  PHF(Ya, Yb);
  // ---- chunk 6 (1,1,0,0) -> (1,1,1,1), n=2, D: B(9) ----
  READS(Ya, Yb, 1,1,0, 1, 0); SB;
  PHB(Xa, Xb);
  LGK(0); VMW(2); BAR; SB;
  STAGE_B(9, 0); SB;
  READS(Xa, Xb, 1,1,1, 0, 1); SB;
  PHF(Ya, Yb);
  // ---- chunk 7 (1,1,1,1) -> (0,0,0,2), n=2, D: B(10) ----
  READS(Ya, Yb, 1,1,1, 1, 1); SB;
  PHB(Xa, Xb);
  LGK(0); VMW(2); BAR; SB;
  STAGE_B(10, 1); SB;
  READS(Xa, Xb, 0,0,0, 0, 2); SB;
  PHF(Ya, Yb);
  // ---- chunk 8 (0,0,0,2) -> (0,0,1,0), n=2, D: B(11)+A(s3) ----
  READS(Ya, Yb, 0,0,0, 1, 2); SB;
  PHB(Xa, Xb);
  LGK(0); VMW(2); BAR; SB;
  STAGE_B(11, 2); STAGE_A(1, 3); SB;
  READS(Xa, Xb, 0,0,1, 0, 0); SB;
  PHF(Ya, Yb);
  // ---- chunk 9 (0,0,1,0) -> (0,1,0,1), n=8, D: B(12) ----
  READS(Ya, Yb, 0,0,1, 1, 0); SB;
  PHB(Xa, Xb);
  LGK(0); VMW(8); BAR; SB;
  STAGE_B(12, 0); SB;
  READS(Xa, Xb, 0,1,0, 0, 1); SB;
  PHF(Ya, Yb);
  // ---- chunk 10 (0,1,0,1) -> (0,1,1,2), n=2, D: B(13) ----
  READS(Ya, Yb, 0,1,0, 1, 1); SB;
  PHB(Xa, Xb);
  LGK(0); VMW(2); BAR; SB;
  STAGE_B(13, 1); SB;
  READS(Xa, Xb, 0,1,1, 0, 2); SB;
  PHF(Ya, Yb);
  // ---- chunk 11 (0,1,1,2) -> (1,0,0,0), n=2, D: B(14) ----
  READS(Ya, Yb, 0,1,1, 1, 2); SB;
  PHB(Xa, Xb);
  LGK(0); VMW(2); BAR; SB;
  STAGE_B(14, 2); SB;
  READS(Xa, Xb, 1,0,0, 0, 0); SB;
  PHF(Ya, Yb);
  // ---- chunk 12 (1,0,0,0) -> (1,0,1,1), n=2, D: B(15) ----
  READS(Ya, Yb, 1,0,0, 1, 0); SB;
  PHB(Xa, Xb);
  LGK(0); VMW(2); BAR; SB;
  STAGE_B(15, 0); SB;
  READS(Xa, Xb, 1,0,1, 0, 1); SB;
  PHF(Ya, Yb);
  // ---- chunk 13 (1,0,1,1) -> (1,1,0,2), n=2, no stage ----
  READS(Ya, Yb, 1,0,1, 1, 1); SB;
  PHB(Xa, Xb);
  LGK(0); VMW(2); BAR; SB;
  READS(Xa, Xb, 1,1,0, 0, 2); SB;
  PHF(Ya, Yb);
  // ---- chunk 14 (1,1,0,2) -> (1,1,1,0), n=0, no stage ----
  READS(Ya, Yb, 1,1,0, 1, 2); SB;
  PHB(Xa, Xb);
  LGK(0); VMW(0); BAR; SB;
  READS(Xa, Xb, 1,1,1, 0, 0); SB;
  PHF(Ya, Yb);
  // ---- chunk 15 (1,1,1,0) — tail ----
  READS(Ya, Yb, 1,1,1, 1, 0); SB;
  PHB(Xa, Xb);
  LGK(0);
  PHF(Ya, Yb);

#undef SB
#undef BAR
#undef VMW
#undef LGK
#undef DSR
#undef STAGE_A
#undef STAGE_B
#undef READS
#undef MFMA16
#undef PHB
#undef PHF

  // ---------------- epilogue ----------------
  float scale = powf(sqrtf(128.f) / log1pf(128.f), alpha[0]);
  float kq[4], bi[4];
  #pragma unroll
  for (int nt = 0; nt < 4; ++nt) {
    int n = coh*64 + nt*16 + l15;
    kq[nt] = ksq[n]; bi[nt] = bias[n];
  }
  int oy = 2*(u4*4 + rp) + py;
  size_t orow = ((size_t)b*128 + oy) * 128 * COUT;
  #pragma unroll
  for (int mt = 0; mt < 4; ++mt) {
    #pragma unroll
    for (int r = 0; r < 4; ++r) {
      int v = mt*16 + l4*4 + r;
      int vpx = v + px;
      float ps = srow[rp*66 + vpx] + srow[rp*66 + vpx + 1]
               + srow[rp*66 + 66 + vpx] + srow[rp*66 + 66 + vpx + 1];
      #pragma unroll
      for (int nt = 0; nt < 4; ++nt) {
        float dot = acc[mt][nt][r];
        float dist = ps + kq[nt] - 2.f*dot + 1e-5f;
        float y = (dot*dot/dist + bi[nt]) * scale;
        int n = coh*64 + nt*16 + l15;
        out[orow + (size_t)(2*v + px)*COUT + n] = y;
      }
    }
  }
}

// ---------------- fallback (tiny ws): direct fp32 ----------------
__global__ __launch_bounds__(256) void fb_ksq(const float* __restrict__ w,
                                              float* __restrict__ ksq) {
  __shared__ float red[256];
  int co = blockIdx.x, t = threadIdx.x;
  float s = 0.f;
  for (int j = t; j < 4096; j += 256) { float v = w[(size_t)j*COUT + co]; s += v*v; }
  red[t] = s; __syncthreads();
  for (int off = 128; off > 0; off >>= 1) {
    if (t < off) red[t] += red[t + off];
    __syncthreads();
  }
  if (t == 0) ksq[co] = red[0];
}

__global__ __launch_bounds__(256) void fb_main(
    const float* __restrict__ x, const float* __restrict__ w,
    const float* __restrict__ bias, const float* __restrict__ alpha,
    const float* __restrict__ ksq, float* __restrict__ out)
{
  size_t idx = (size_t)blockIdx.x * 256 + threadIdx.x;
  int co = (int)(idx & 127);
  int ox = (int)((idx >> 7) & 127);
  int oy = (int)((idx >> 14) & 127);
  int b  = (int)(idx >> 21);
  int py = oy & 1, px = ox & 1, u = oy >> 1, v = ox >> 1;
  float dot = 0.f, ps = 0.f;
  for (int a = 0; a < 2; ++a) {
    int iy = u + py + a - 1;
    if (iy < 0 || iy > 63) continue;
    for (int b2 = 0; b2 < 2; ++b2) {
      int ix = v + px + b2 - 1;
      if (ix < 0 || ix > 63) continue;
      const float* xp = x + (((size_t)b*64 + iy)*64 + ix)*CIN;
      const float* wp = w + ((size_t)((py + 2*a)*4 + (px + 2*b2))*CIN)*COUT + co;
      for (int ci = 0; ci < CIN; ++ci) {
        float xv = xp[ci];
        dot += xv * wp[(size_t)ci*COUT];
        ps  += xv * xv;
      }
    }
  }
  float dist = ps + ksq[co] - 2.f*dot + 1e-5f;
  float scale = powf(sqrtf(128.f) / log1pf(128.f), alpha[0]);
  out[idx] = (dot*dot/dist + bias[co]) * scale;
}

// ---------------- launcher ----------------
extern "C" void kernel_launch(void* const* d_in, const int* in_sizes, int n_in,
                              void* d_out, int out_size, void* d_ws, size_t ws_size,
                              hipStream_t stream)
{
  const float* x     = (const float*)d_in[0];
  const float* w     = (const float*)d_in[1];
  const float* bias  = (const float*)d_in[2];
  const float* alpha = (const float*)d_in[3];
  float* out = (float*)d_out;

  if (ws_size < WS_NEEDED) {
    float* ksq = (float*)d_ws;
    fb_ksq<<<128, 256, 0, stream>>>(w, ksq);
    fb_main<<<131072, 256, 0, stream>>>(x, w, bias, alpha, ksq, out);
    return;
  }

  unsigned short* xpad = (unsigned short*)d_ws;
  unsigned short* wtp  = (unsigned short*)((char*)d_ws + WT_OFF);
  float* spad = (float*)((char*)d_ws + SPAD_OFF);
  float* ksq  = (float*)((char*)d_ws + KSQ_OFF);

  hipMemsetAsync(ksq, 0, 512, stream);
  prep_x<<<17424, 256, 0, stream>>>(x, xpad, spad);
  prep_w<<<128, 256, 0, stream>>>(w, wtp, ksq);
  yat_main<<<1024, 512, 0, stream>>>(xpad, wtp, spad, ksq, bias, alpha, out);
}

// Round 16
// 103.469 us; speedup vs baseline: 1.1575x; 1.1346x over previous
//
#include <hip/hip_runtime.h>
#include <cstdint>
#include <cstddef>

#define CIN   256
#define COUT  128

typedef float  f32x4  __attribute__((ext_vector_type(4)));
typedef __bf16 bf16x8 __attribute__((ext_vector_type(8)));
typedef unsigned int u32x4 __attribute__((ext_vector_type(4)));

// ---------------- workspace layout (bytes) ----------------
#define XPAD_BYTES (16ull*66*66*256*2)          // 35,684,352  bf16 padded x
#define WT_OFF     XPAD_BYTES
#define WT_BYTES   (16ull*128*256*2)            // 1,048,576   bf16 w, [tap][co][ci]
#define SPAD_OFF   (WT_OFF + WT_BYTES)
#define SPAD_BYTES (16ull*66*66*4)              // 278,784     fp32 per-pixel sum(x^2)
#define KSQ_OFF    (SPAD_OFF + SPAD_BYTES)
#define WS_NEEDED  (KSQ_OFF + 512)

__device__ __forceinline__ unsigned short f2bf(float f) {
  unsigned int u = __float_as_uint(f);
  u += 0x7fffu + ((u >> 16) & 1u);              // RNE
  return (unsigned short)(u >> 16);
}

__device__ __forceinline__ void async16(const void* lds, const void* g) {
  __builtin_amdgcn_global_load_lds(
      (const __attribute__((address_space(1))) unsigned int*)g,
      (__attribute__((address_space(3))) unsigned int*)lds, 16, 0, 0);
}

// ---------------- fused prep: pad x + spad | wt transpose | ksq ----------
// blocks [0,17424): prep_x; [17424,17552): prep_w; [17552,17680): ksq
__global__ __launch_bounds__(256) void prep_all(
    const float* __restrict__ x, const float* __restrict__ w,
    unsigned short* __restrict__ xpad, unsigned short* __restrict__ wt,
    float* __restrict__ spad, float* __restrict__ ksq)
{
  __shared__ __align__(16) unsigned short lw[32*128];
  __shared__ float red[256];
  int blk = blockIdx.x;
  int t = threadIdx.x;

  if (blk < 17424) {
    // ---- prep_x (R5-verified) ----
    int wave = t >> 6, lane = t & 63;
    int p = blk * 4 + wave;                      // 0..69695 over [16][66][66]
    int b = p / 4356;
    int rem = p - b * 4356;
    int iyp = rem / 66, ixp = rem - iyp * 66;
    bool interior = (iyp >= 1 && iyp <= 64 && ixp >= 1 && ixp <= 64);
    f32x4 v = {0.f, 0.f, 0.f, 0.f};
    if (interior) {
      const float* src = x + (((size_t)b*64 + (iyp-1))*64 + (ixp-1))*CIN + lane*4;
      v = *(const f32x4*)src;
    }
    ushort4 h;
    h.x = f2bf(v.x); h.y = f2bf(v.y); h.z = f2bf(v.z); h.w = f2bf(v.w);
    *(ushort4*)(xpad + (size_t)p*CIN + lane*4) = h;
    float s = v.x*v.x + v.y*v.y + v.z*v.z + v.w*v.w;
    #pragma unroll
    for (int off = 32; off > 0; off >>= 1) s += __shfl_down(s, off);
    if (lane == 0) spad[p] = s;
  } else if (blk < 17552) {
    // ---- prep_w: wt[tap][co][ci] (R5-verified, atomics stripped) ----
    int pblk = blk - 17424;
    int tap = pblk >> 3;
    int ci0 = (pblk & 7) * 32;
    int co4 = (t & 31) * 4;
    #pragma unroll
    for (int i = 0; i < 4; ++i) {
      int ci = (t >> 5) + i*8;
      const float* src = w + ((size_t)(tap*256 + ci0 + ci))*COUT + co4;
      f32x4 v = *(const f32x4*)src;
      ushort4 h; h.x = f2bf(v.x); h.y = f2bf(v.y); h.z = f2bf(v.z); h.w = f2bf(v.w);
      *(ushort4*)&lw[ci*128 + co4] = h;
    }
    __syncthreads();
    int co = t >> 1, h16 = (t & 1) * 16;
    union { unsigned short u[16]; uint4 q[2]; } tmp;
    #pragma unroll
    for (int i = 0; i < 16; ++i) tmp.u[i] = lw[(h16 + i)*128 + co];
    uint4* dst = (uint4*)(wt + ((size_t)tap*128 + co)*CIN + ci0 + h16);
    dst[0] = tmp.q[0]; dst[1] = tmp.q[1];
  } else {
    // ---- ksq (reduction, no atomics) ----
    int co = blk - 17552;
    float s = 0.f;
    for (int j = t; j < 4096; j += 256) { float v = w[(size_t)j*COUT + co]; s += v*v; }
    red[t] = s; __syncthreads();
    for (int off = 128; off > 0; off >>= 1) {
      if (t < off) red[t] += red[t + off];
      __syncthreads();
    }
    if (t == 0) ksq[co] = red[0];
  }
}

// ---------------- main fused kernel (3 blocks/CU, m97-style TLP) ----------
// grid = 2048: bid -> px=bid&1, py=(bid>>1)&1, u2=(bid>>2)&31, b=bid>>7
// block = 256 (4 waves): wave = rp*2+coh; wave tile 64 v x 64 co, u-row rp.
// 32 chunks: c -> s=c>>2 (ci-32), a=(c>>1)&1, bb=c&1.
// A: [3 rows][66 col][32 ci] XOR-swizzled, depth-2 (13312 B each).
// B: [128 co][32 ci] XOR-swizzled, depth-3 (8192 B each). LDS total 52 KB.
// Stage distance: B +2 chunks, A +4; counted VMW {2,6,6,2}x7 + {2,2,2,0}.
__global__ __launch_bounds__(256, 3) void yat_main(
    const unsigned short* __restrict__ xpad,
    const unsigned short* __restrict__ wt,
    const float* __restrict__ spad,
    const float* __restrict__ ksq,
    const float* __restrict__ bias,
    const float* __restrict__ alpha,
    float* __restrict__ out)
{
  __shared__ __align__(16) unsigned short xsA[2][6656];   // 2 x 13312 B
  __shared__ __align__(16) unsigned short xsB[3][4096];   // 3 x 8192 B
  __shared__ float srow[198];

  int orig = blockIdx.x;
  int bid = (orig & 7) * 256 + (orig >> 3);               // XCD-contiguous
  int px = bid & 1, py = (bid >> 1) & 1, u2 = (bid >> 2) & 31, b = bid >> 7;
  int t = threadIdx.x, wave = t >> 6, lane = t & 63;
  int rp = wave >> 1, coh = wave & 1;
  int l15 = lane & 15, l4 = lane >> 4;
  int bRow0 = 2*u2 + py;

  if (t < 198) {
    int r = t / 66, c = t - r*66;
    srow[t] = spad[((size_t)b*66 + bRow0 + r)*66 + c];
  }
  asm volatile("s_waitcnt vmcnt(0) lgkmcnt(0)" ::: "memory");

  // ---- A staging: 792 valid 16B segs + pad; 4 rounds x 4 waves ----
  // seg = (row*66 + col)*4 + q; content swizzle q_src = q ^ (col&3)
  const char* srcA[4];
  unsigned short* dstA[4];
  {
    #pragma unroll
    for (int r = 0; r < 3; ++r) {
      int seg = r*256 + t;
      int row = seg / 264; int r2 = seg - row*264;
      int col = r2 >> 2, q = r2 & 3;
      srcA[r] = (const char*)xpad
              + (((size_t)(b*66 + bRow0 + row))*66 + col)*512 + ((q ^ (col&3))*16);
      dstA[r] = &xsA[0][0] + (size_t)(r*2048 + wave*512);  // shorts: r*4096B+w*1024B
    }
    int l = t & 63;
    int seg = 768 + ((l < 24) ? l : 23);                   // clamp (dup content)
    int row = seg / 264; int r2 = seg - row*264;
    int col = r2 >> 2, q = r2 & 3;
    srcA[3] = (const char*)xpad
            + (((size_t)(b*66 + bRow0 + row))*66 + col)*512 + ((q ^ (col&3))*16);
    dstA[3] = &xsA[0][0] + 6144;                           // byte 12288, all waves
  }
  // ---- B staging: 512 segs; 2 rounds x 4 waves ----
  const char* srcB[2];
  unsigned short* dstB[2];
  {
    int baseTap = py*4 + px;
    #pragma unroll
    for (int r = 0; r < 2; ++r) {
      int seg = r*256 + t;
      int co = seg >> 2, qd = seg & 3;
      srcB[r] = (const char*)wt + (size_t)baseTap*65536
              + (size_t)co*512 + ((qd ^ (co&3))*16);
      dstB[r] = &xsB[0][0] + (size_t)(r*2048 + wave*512);  // r*4096B + w*1024B
    }
  }

  // ---- per-lane ds_read bases (swizzled) ----
  unsigned abA[2];
  #pragma unroll
  for (int bb = 0; bb < 2; ++bb) {
    int c0 = l15 + px + bb;
    abA[bb] = (unsigned)(size_t)(&xsA[0][0])
            + (unsigned)(rp*4224 + c0*64 + ((l4 ^ (c0&3)) << 4));
  }
  unsigned abB = (unsigned)(size_t)(&xsB[0][0])
               + (unsigned)((coh*64 + l15)*64 + ((l4 ^ (l15&3)) << 4));

  f32x4 acc[4][4];
  #pragma unroll
  for (int i = 0; i < 4; ++i)
    #pragma unroll
    for (int j = 0; j < 4; ++j)
      acc[i][j] = (f32x4){0.f, 0.f, 0.f, 0.f};

  u32x4 Af[4], Bf[4];

#define SB  __builtin_amdgcn_sched_barrier(0)
#define BAR __builtin_amdgcn_s_barrier()
#define VMW(N) do { asm volatile("s_waitcnt vmcnt(" #N ")" ::: "memory"); SB; } while (0)
#define LGK(N) do { asm volatile("s_waitcnt lgkmcnt(" #N ")" ::: "memory"); SB; } while (0)
#define DSR(dst, addr, off)                                                \
  asm volatile("ds_read_b128 %0, %1 offset:%c2"                            \
               : "=v"(dst) : "v"(addr), "i"(off))

  // B-stage for chunk c2: BI2*8192 dst; src + a2*524288 + bb2*131072 + s2*64
#define STG_B(BI2, OFF) {                                                  \
    async16(dstB[0] + (size_t)(BI2)*4096, srcB[0] + (OFF));                \
    async16(dstB[1] + (size_t)(BI2)*4096, srcB[1] + (OFF)); }
  // A-stage for superchunk s2: buf (s2&1); src + s2*64
#define STG_A(BUF2, OFF) {                                                 \
    async16(dstA[0] + (size_t)(BUF2)*6656, srcA[0] + (OFF));               \
    async16(dstA[1] + (size_t)(BUF2)*6656, srcA[1] + (OFF));               \
    async16(dstA[2] + (size_t)(BUF2)*6656, srcA[2] + (OFF));               \
    async16(dstA[3] + (size_t)(BUF2)*6656, srcA[3] + (OFF)); }

#define MFMA16 {                                                           \
    _Pragma("unroll")                                                      \
    for (int mt = 0; mt < 4; ++mt)                                         \
      _Pragma("unroll")                                                    \
      for (int nt = 0; nt < 4; ++nt)                                       \
        acc[mt][nt] = __builtin_amdgcn_mfma_f32_16x16x32_bf16(             \
            __builtin_bit_cast(bf16x8, Af[mt]),                            \
            __builtin_bit_cast(bf16x8, Bf[nt]),                            \
            acc[mt][nt], 0, 0, 0); }

  // one chunk: N=vmcnt, BUFA/AA/BB = A-read params, BI = B-read buf,
  // optional B-stage (DOB, BI2, OFFB) and A-stage (DOA, BUFA2, OFFA)
#define CH(N, BUFA, AA, BB, BI, DOB, BI2, OFFB, DOA, BUFA2, OFFA) {        \
    VMW(N); BAR;                                                           \
    DSR(Af[0], abA[BB], (BUFA)*13312 + (AA)*4224 + 0);                     \
    DSR(Af[1], abA[BB], (BUFA)*13312 + (AA)*4224 + 1024);                  \
    DSR(Af[2], abA[BB], (BUFA)*13312 + (AA)*4224 + 2048);                  \
    DSR(Af[3], abA[BB], (BUFA)*13312 + (AA)*4224 + 3072);                  \
    DSR(Bf[0], abB, (BI)*8192 + 0);                                        \
    DSR(Bf[1], abB, (BI)*8192 + 1024);                                     \
    DSR(Bf[2], abB, (BI)*8192 + 2048);                                     \
    DSR(Bf[3], abB, (BI)*8192 + 3072);                                     \
    SB;                                                                    \
    if (DOB) STG_B(BI2, OFFB);                                             \
    if (DOA) STG_A(BUFA2, OFFA);                                           \
    SB;                                                                    \
    LGK(0);                                                                \
    __builtin_amdgcn_s_setprio(1); MFMA16;                                 \
    __builtin_amdgcn_s_setprio(0); SB; }

  SB;
  // ---- prologue: B(c0)->BI0, A(s0)->buf0, B(c1)->BI1 ----
  STG_B(0, 0);
  STG_A(0, 0);
  STG_B(1, 131072);
  SB;

  //  N  bufA a bb BI | B2? BI2 OFFB                  | A2? buf2 OFFA
  CH(2, 0,0,0, 0,  1, 2, 524288,                1, 1, 64);        // c0
  CH(6, 0,0,1, 1,  1, 0, 524288+131072,         0, 0, 0);         // c1
  CH(6, 0,1,0, 2,  1, 1, 64,                    0, 0, 0);         // c2
  CH(2, 0,1,1, 0,  1, 2, 131072+64,             0, 0, 0);         // c3
  CH(2, 1,0,0, 1,  1, 0, 524288+64,             1, 0, 128);       // c4
  CH(6, 1,0,1, 2,  1, 1, 524288+131072+64,      0, 0, 0);         // c5
  CH(6, 1,1,0, 0,  1, 2, 128,                   0, 0, 0);         // c6
  CH(2, 1,1,1, 1,  1, 0, 131072+128,            0, 0, 0);         // c7
  CH(2, 0,0,0, 2,  1, 1, 524288+128,            1, 1, 192);       // c8
  CH(6, 0,0,1, 0,  1, 2, 524288+131072+128,     0, 0, 0);         // c9
  CH(6, 0,1,0, 1,  1, 0, 192,                   0, 0, 0);         // c10
  CH(2, 0,1,1, 2,  1, 1, 131072+192,            0, 0, 0);         // c11
  CH(2, 1,0,0, 0,  1, 2, 524288+192,            1, 0, 256);       // c12
  CH(6, 1,0,1, 1,  1, 0, 524288+131072+192,     0, 0, 0);         // c13
  CH(6, 1,1,0, 2,  1, 1, 256,                   0, 0, 0);         // c14
  CH(2, 1,1,1, 0,  1, 2, 131072+256,            0, 0, 0);         // c15
  CH(2, 0,0,0, 1,  1, 0, 524288+256,            1, 1, 320);       // c16
  CH(6, 0,0,1, 2,  1, 1, 524288+131072+256,     0, 0, 0);         // c17
  CH(6, 0,1,0, 0,  1, 2, 320,                   0, 0, 0);         // c18
  CH(2, 0,1,1, 1,  1, 0, 131072+320,            0, 0, 0);         // c19
  CH(2, 1,0,0, 2,  1, 1, 524288+320,            1, 0, 384);       // c20
  CH(6, 1,0,1, 0,  1, 2, 524288+131072+320,     0, 0, 0);         // c21
  CH(6, 1,1,0, 1,  1, 0, 384,                   0, 0, 0);         // c22
  CH(2, 1,1,1, 2,  1, 1, 131072+384,            0, 0, 0);         // c23
  CH(2, 0,0,0, 0,  1, 2, 524288+384,            1, 1, 448);       // c24
  CH(6, 0,0,1, 1,  1, 0, 524288+131072+384,     0, 0, 0);         // c25
  CH(6, 0,1,0, 2,  1, 1, 448,                   0, 0, 0);         // c26
  CH(2, 0,1,1, 0,  1, 2, 131072+448,            0, 0, 0);         // c27
  CH(2, 1,0,0, 1,  1, 0, 524288+448,            0, 0, 0);         // c28
  CH(2, 1,0,1, 2,  1, 1, 524288+131072+448,     0, 0, 0);         // c29
  CH(2, 1,1,0, 0,  0, 0, 0,                     0, 0, 0);         // c30
  CH(0, 1,1,1, 1,  0, 0, 0,                     0, 0, 0);         // c31

#undef SB
#undef BAR
#undef VMW
#undef LGK
#undef DSR
#undef STG_B
#undef STG_A
#undef MFMA16
#undef CH

  // ---------------- epilogue ----------------
  float scale = powf(sqrtf(128.f) / log1pf(128.f), alpha[0]);
  float kq[4], bi[4];
  #pragma unroll
  for (int nt = 0; nt < 4; ++nt) {
    int n = coh*64 + nt*16 + l15;
    kq[nt] = ksq[n]; bi[nt] = bias[n];
  }
  int oy = 2*(2*u2 + rp) + py;
  size_t orow = ((size_t)b*128 + oy) * 128 * COUT;
  #pragma unroll
  for (int mt = 0; mt < 4; ++mt) {
    #pragma unroll
    for (int r = 0; r < 4; ++r) {
      int v = mt*16 + l4*4 + r;
      int vpx = v + px;
      float ps = srow[rp*66 + vpx] + srow[rp*66 + vpx + 1]
               + srow[rp*66 + 66 + vpx] + srow[rp*66 + 66 + vpx + 1];
      #pragma unroll
      for (int nt = 0; nt < 4; ++nt) {
        float dot = acc[mt][nt][r];
        float dist = ps + kq[nt] - 2.f*dot + 1e-5f;
        float y = (dot*dot/dist + bi[nt]) * scale;
        int n = coh*64 + nt*16 + l15;
        out[orow + (size_t)(2*v + px)*COUT + n] = y;
      }
    }
  }
}

// ---------------- fallback (tiny ws): direct fp32 ----------------
__global__ __launch_bounds__(256) void fb_ksq(const float* __restrict__ w,
                                              float* __restrict__ ksq) {
  __shared__ float red[256];
  int co = blockIdx.x, t = threadIdx.x;
  float s = 0.f;
  for (int j = t; j < 4096; j += 256) { float v = w[(size_t)j*COUT + co]; s += v*v; }
  red[t] = s; __syncthreads();
  for (int off = 128; off > 0; off >>= 1) {
    if (t < off) red[t] += red[t + off];
    __syncthreads();
  }
  if (t == 0) ksq[co] = red[0];
}

__global__ __launch_bounds__(256) void fb_main(
    const float* __restrict__ x, const float* __restrict__ w,
    const float* __restrict__ bias, const float* __restrict__ alpha,
    const float* __restrict__ ksq, float* __restrict__ out)
{
  size_t idx = (size_t)blockIdx.x * 256 + threadIdx.x;
  int co = (int)(idx & 127);
  int ox = (int)((idx >> 7) & 127);
  int oy = (int)((idx >> 14) & 127);
  int b  = (int)(idx >> 21);
  int py = oy & 1, px = ox & 1, u = oy >> 1, v = ox >> 1;
  float dot = 0.f, ps = 0.f;
  for (int a = 0; a < 2; ++a) {
    int iy = u + py + a - 1;
    if (iy < 0 || iy > 63) continue;
    for (int b2 = 0; b2 < 2; ++b2) {
      int ix = v + px + b2 - 1;
      if (ix < 0 || ix > 63) continue;
      const float* xp = x + (((size_t)b*64 + iy)*64 + ix)*CIN;
      const float* wp = w + ((size_t)((py + 2*a)*4 + (px + 2*b2))*CIN)*COUT + co;
      for (int ci = 0; ci < CIN; ++ci) {
        float xv = xp[ci];
        dot += xv * wp[(size_t)ci*COUT];
        ps  += xv * xv;
      }
    }
  }
  float dist = ps + ksq[co] - 2.f*dot + 1e-5f;
  float scale = powf(sqrtf(128.f) / log1pf(128.f), alpha[0]);
  out[idx] = (dot*dot/dist + bias[co]) * scale;
}

// ---------------- launcher ----------------
extern "C" void kernel_launch(void* const* d_in, const int* in_sizes, int n_in,
                              void* d_out, int out_size, void* d_ws, size_t ws_size,
                              hipStream_t stream)
{
  const float* x     = (const float*)d_in[0];
  const float* w     = (const float*)d_in[1];
  const float* bias  = (const float*)d_in[2];
  const float* alpha = (const float*)d_in[3];
  float* out = (float*)d_out;

  if (ws_size < WS_NEEDED) {
    float* ksq = (float*)d_ws;
    fb_ksq<<<128, 256, 0, stream>>>(w, ksq);
    fb_main<<<131072, 256, 0, stream>>>(x, w, bias, alpha, ksq, out);
    return;
  }

  unsigned short* xpad = (unsigned short*)d_ws;
  unsigned short* wtp  = (unsigned short*)((char*)d_ws + WT_OFF);
  float* spad = (float*)((char*)d_ws + SPAD_OFF);
  float* ksq  = (float*)((char*)d_ws + KSQ_OFF);

  prep_all<<<17680, 256, 0, stream>>>(x, w, xpad, wtp, spad, ksq);
  yat_main<<<2048, 256, 0, stream>>>(xpad, wtp, spad, ksq, bias, alpha, out);
}

// Round 17
// 103.043 us; speedup vs baseline: 1.1623x; 1.0041x over previous
//
#include <hip/hip_runtime.h>
#include <cstdint>
#include <cstddef>

#define CIN   256
#define COUT  128

typedef float  f32x4  __attribute__((ext_vector_type(4)));
typedef __bf16 bf16x8 __attribute__((ext_vector_type(8)));
typedef unsigned int u32x4 __attribute__((ext_vector_type(4)));

// ---------------- workspace layout (bytes) ----------------
#define XPAD_BYTES (16ull*66*66*256*2)          // 35,684,352  bf16 padded x
#define WT_OFF     XPAD_BYTES
#define WT_BYTES   (16ull*128*256*2)            // 1,048,576   bf16 w, [tap][co][ci]
#define SPAD_OFF   (WT_OFF + WT_BYTES)
#define SPAD_BYTES (16ull*66*66*4)              // 278,784     fp32 per-pixel sum(x^2)
#define KSQ_OFF    (SPAD_OFF + SPAD_BYTES)
#define WS_NEEDED  (KSQ_OFF + 512)

__device__ __forceinline__ unsigned short f2bf(float f) {
  unsigned int u = __float_as_uint(f);
  u += 0x7fffu + ((u >> 16) & 1u);              // RNE
  return (unsigned short)(u >> 16);
}

__device__ __forceinline__ void async16(const void* lds, const void* g) {
  __builtin_amdgcn_global_load_lds(
      (const __attribute__((address_space(1))) unsigned int*)g,
      (__attribute__((address_space(3))) unsigned int*)lds, 16, 0, 0);
}

// ---------------- fused prep: pad x + spad | wt transpose | ksq ----------
// blocks [0,17424): prep_x; [17424,17552): prep_w; [17552,17680): ksq
__global__ __launch_bounds__(256) void prep_all(
    const float* __restrict__ x, const float* __restrict__ w,
    unsigned short* __restrict__ xpad, unsigned short* __restrict__ wt,
    float* __restrict__ spad, float* __restrict__ ksq)
{
  __shared__ __align__(16) unsigned short lw[32*128];
  __shared__ float red[256];
  int blk = blockIdx.x;
  int t = threadIdx.x;

  if (blk < 17424) {
    // ---- prep_x (R5-verified) ----
    int wave = t >> 6, lane = t & 63;
    int p = blk * 4 + wave;                      // 0..69695 over [16][66][66]
    int b = p / 4356;
    int rem = p - b * 4356;
    int iyp = rem / 66, ixp = rem - iyp * 66;
    bool interior = (iyp >= 1 && iyp <= 64 && ixp >= 1 && ixp <= 64);
    f32x4 v = {0.f, 0.f, 0.f, 0.f};
    if (interior) {
      const float* src = x + (((size_t)b*64 + (iyp-1))*64 + (ixp-1))*CIN + lane*4;
      v = *(const f32x4*)src;
    }
    ushort4 h;
    h.x = f2bf(v.x); h.y = f2bf(v.y); h.z = f2bf(v.z); h.w = f2bf(v.w);
    *(ushort4*)(xpad + (size_t)p*CIN + lane*4) = h;
    float s = v.x*v.x + v.y*v.y + v.z*v.z + v.w*v.w;
    #pragma unroll
    for (int off = 32; off > 0; off >>= 1) s += __shfl_down(s, off);
    if (lane == 0) spad[p] = s;
  } else if (blk < 17552) {
    // ---- prep_w: wt[tap][co][ci] (R5-verified, atomics stripped) ----
    int pblk = blk - 17424;
    int tap = pblk >> 3;
    int ci0 = (pblk & 7) * 32;
    int co4 = (t & 31) * 4;
    #pragma unroll
    for (int i = 0; i < 4; ++i) {
      int ci = (t >> 5) + i*8;
      const float* src = w + ((size_t)(tap*256 + ci0 + ci))*COUT + co4;
      f32x4 v = *(const f32x4*)src;
      ushort4 h; h.x = f2bf(v.x); h.y = f2bf(v.y); h.z = f2bf(v.z); h.w = f2bf(v.w);
      *(ushort4*)&lw[ci*128 + co4] = h;
    }
    __syncthreads();
    int co = t >> 1, h16 = (t & 1) * 16;
    union { unsigned short u[16]; uint4 q[2]; } tmp;
    #pragma unroll
    for (int i = 0; i < 16; ++i) tmp.u[i] = lw[(h16 + i)*128 + co];
    uint4* dst = (uint4*)(wt + ((size_t)tap*128 + co)*CIN + ci0 + h16);
    dst[0] = tmp.q[0]; dst[1] = tmp.q[1];
  } else {
    // ---- ksq (reduction, no atomics) ----
    int co = blk - 17552;
    float s = 0.f;
    for (int j = t; j < 4096; j += 256) { float v = w[(size_t)j*COUT + co]; s += v*v; }
    red[t] = s; __syncthreads();
    for (int off = 128; off > 0; off >>= 1) {
      if (t < off) red[t] += red[t + off];
      __syncthreads();
    }
    if (t == 0) ksq[co] = red[0];
  }
}

// ---------------- main fused kernel (3 blocks/CU, m97-style TLP) ----------
// grid = 2048: bid -> px=bid&1, py=(bid>>1)&1, u2=(bid>>2)&31, b=bid>>7
// block = 256 (4 waves): wave = rp*2+coh; wave tile 64 v x 64 co, u-row rp.
// 32 chunks: c -> s=c>>2 (ci-32), a=(c>>1)&1, bb=c&1.
// A: [3 rows][66 col][32 ci], depth-2 (13312 B each).
// B: [128 co][32 ci], depth-3 (8192 B each). LDS total 52 KB.
// Swizzle f(col) = (col>>1)&3 (R16 used col&3 -> 4-way bank conflict; cols
// c, c+4, c+8, c+12 hit identical banks. (col>>1)&3 spreads same-parity cols
// over all 4 q-slots -> 2-way = free).
// Stage distance: B +2 chunks, A +4; counted VMW {2,6,6,2}x7 + {2,2,2,0}.
__global__ __launch_bounds__(256, 3) void yat_main(
    const unsigned short* __restrict__ xpad,
    const unsigned short* __restrict__ wt,
    const float* __restrict__ spad,
    const float* __restrict__ ksq,
    const float* __restrict__ bias,
    const float* __restrict__ alpha,
    float* __restrict__ out)
{
  __shared__ __align__(16) unsigned short xsA[2][6656];   // 2 x 13312 B
  __shared__ __align__(16) unsigned short xsB[3][4096];   // 3 x 8192 B
  __shared__ float srow[198];

  int orig = blockIdx.x;
  int bid = (orig & 7) * 256 + (orig >> 3);               // XCD-contiguous
  int px = bid & 1, py = (bid >> 1) & 1, u2 = (bid >> 2) & 31, b = bid >> 7;
  int t = threadIdx.x, wave = t >> 6, lane = t & 63;
  int rp = wave >> 1, coh = wave & 1;
  int l15 = lane & 15, l4 = lane >> 4;
  int bRow0 = 2*u2 + py;

  if (t < 198) {
    int r = t / 66, c = t - r*66;
    srow[t] = spad[((size_t)b*66 + bRow0 + r)*66 + c];
  }
  asm volatile("s_waitcnt vmcnt(0) lgkmcnt(0)" ::: "memory");

  // ---- A staging: 792 valid 16B segs + pad; 4 rounds x 4 waves ----
  // seg = (row*66 + col)*4 + q; content swizzle q_src = q ^ ((col>>1)&3)
  const char* srcA[4];
  unsigned short* dstA[4];
  {
    #pragma unroll
    for (int r = 0; r < 3; ++r) {
      int seg = r*256 + t;
      int row = seg / 264; int r2 = seg - row*264;
      int col = r2 >> 2, q = r2 & 3;
      srcA[r] = (const char*)xpad
              + (((size_t)(b*66 + bRow0 + row))*66 + col)*512
              + ((q ^ ((col>>1)&3))*16);
      dstA[r] = &xsA[0][0] + (size_t)(r*2048 + wave*512);  // shorts: r*4096B+w*1024B
    }
    int l = t & 63;
    int seg = 768 + ((l < 24) ? l : 23);                   // clamp (dup content)
    int row = seg / 264; int r2 = seg - row*264;
    int col = r2 >> 2, q = r2 & 3;
    srcA[3] = (const char*)xpad
            + (((size_t)(b*66 + bRow0 + row))*66 + col)*512
            + ((q ^ ((col>>1)&3))*16);
    dstA[3] = &xsA[0][0] + 6144;                           // byte 12288, all waves
  }
  // ---- B staging: 512 segs; 2 rounds x 4 waves ----
  const char* srcB[2];
  unsigned short* dstB[2];
  {
    int baseTap = py*4 + px;
    #pragma unroll
    for (int r = 0; r < 2; ++r) {
      int seg = r*256 + t;
      int co = seg >> 2, qd = seg & 3;
      srcB[r] = (const char*)wt + (size_t)baseTap*65536
              + (size_t)co*512 + ((qd ^ ((co>>1)&3))*16);
      dstB[r] = &xsB[0][0] + (size_t)(r*2048 + wave*512);  // r*4096B + w*1024B
    }
  }

  // ---- per-lane ds_read bases (swizzled, f = (col>>1)&3) ----
  unsigned abA[2];
  #pragma unroll
  for (int bb = 0; bb < 2; ++bb) {
    int c0 = l15 + px + bb;
    abA[bb] = (unsigned)(size_t)(&xsA[0][0])
            + (unsigned)(rp*4224 + c0*64 + ((l4 ^ ((c0>>1)&3)) << 4));
  }
  unsigned abB = (unsigned)(size_t)(&xsB[0][0])
               + (unsigned)((coh*64 + l15)*64 + ((l4 ^ ((l15>>1)&3)) << 4));

  f32x4 acc[4][4];
  #pragma unroll
  for (int i = 0; i < 4; ++i)
    #pragma unroll
    for (int j = 0; j < 4; ++j)
      acc[i][j] = (f32x4){0.f, 0.f, 0.f, 0.f};

  u32x4 Af[4], Bf[4];

#define SB  __builtin_amdgcn_sched_barrier(0)
#define BAR __builtin_amdgcn_s_barrier()
#define VMW(N) do { asm volatile("s_waitcnt vmcnt(" #N ")" ::: "memory"); SB; } while (0)
#define LGK(N) do { asm volatile("s_waitcnt lgkmcnt(" #N ")" ::: "memory"); SB; } while (0)
#define DSR(dst, addr, off)                                                \
  asm volatile("ds_read_b128 %0, %1 offset:%c2"                            \
               : "=v"(dst) : "v"(addr), "i"(off))

  // B-stage for chunk c2: BI2*8192 dst; src + a2*524288 + bb2*131072 + s2*64
#define STG_B(BI2, OFF) {                                                  \
    async16(dstB[0] + (size_t)(BI2)*4096, srcB[0] + (OFF));                \
    async16(dstB[1] + (size_t)(BI2)*4096, srcB[1] + (OFF)); }
  // A-stage for superchunk s2: buf (s2&1); src + s2*64
#define STG_A(BUF2, OFF) {                                                 \
    async16(dstA[0] + (size_t)(BUF2)*6656, srcA[0] + (OFF));               \
    async16(dstA[1] + (size_t)(BUF2)*6656, srcA[1] + (OFF));               \
    async16(dstA[2] + (size_t)(BUF2)*6656, srcA[2] + (OFF));               \
    async16(dstA[3] + (size_t)(BUF2)*6656, srcA[3] + (OFF)); }

#define MFMA16 {                                                           \
    _Pragma("unroll")                                                      \
    for (int mt = 0; mt < 4; ++mt)                                         \
      _Pragma("unroll")                                                    \
      for (int nt = 0; nt < 4; ++nt)                                       \
        acc[mt][nt] = __builtin_amdgcn_mfma_f32_16x16x32_bf16(             \
            __builtin_bit_cast(bf16x8, Af[mt]),                            \
            __builtin_bit_cast(bf16x8, Bf[nt]),                            \
            acc[mt][nt], 0, 0, 0); }

  // one chunk: N=vmcnt, BUFA/AA/BB = A-read params, BI = B-read buf,
  // optional B-stage (DOB, BI2, OFFB) and A-stage (DOA, BUFA2, OFFA)
#define CH(N, BUFA, AA, BB, BI, DOB, BI2, OFFB, DOA, BUFA2, OFFA) {        \
    VMW(N); BAR;                                                           \
    DSR(Af[0], abA[BB], (BUFA)*13312 + (AA)*4224 + 0);                     \
    DSR(Af[1], abA[BB], (BUFA)*13312 + (AA)*4224 + 1024);                  \
    DSR(Af[2], abA[BB], (BUFA)*13312 + (AA)*4224 + 2048);                  \
    DSR(Af[3], abA[BB], (BUFA)*13312 + (AA)*4224 + 3072);                  \
    DSR(Bf[0], abB, (BI)*8192 + 0);                                        \
    DSR(Bf[1], abB, (BI)*8192 + 1024);                                     \
    DSR(Bf[2], abB, (BI)*8192 + 2048);                                     \
    DSR(Bf[3], abB, (BI)*8192 + 3072);                                     \
    SB;                                                                    \
    if (DOB) STG_B(BI2, OFFB);                                             \
    if (DOA) STG_A(BUFA2, OFFA);                                           \
    SB;                                                                    \
    LGK(0);                                                                \
    __builtin_amdgcn_s_setprio(1); MFMA16;                                 \
    __builtin_amdgcn_s_setprio(0); SB; }

  SB;
  // ---- prologue: B(c0)->BI0, A(s0)->buf0, B(c1)->BI1 ----
  STG_B(0, 0);
  STG_A(0, 0);
  STG_B(1, 131072);
  SB;

  //  N  bufA a bb BI | B2? BI2 OFFB                  | A2? buf2 OFFA
  CH(2, 0,0,0, 0,  1, 2, 524288,                1, 1, 64);        // c0
  CH(6, 0,0,1, 1,  1, 0, 524288+131072,         0, 0, 0);         // c1
  CH(6, 0,1,0, 2,  1, 1, 64,                    0, 0, 0);         // c2
  CH(2, 0,1,1, 0,  1, 2, 131072+64,             0, 0, 0);         // c3
  CH(2, 1,0,0, 1,  1, 0, 524288+64,             1, 0, 128);       // c4
  CH(6, 1,0,1, 2,  1, 1, 524288+131072+64,      0, 0, 0);         // c5
  CH(6, 1,1,0, 0,  1, 2, 128,                   0, 0, 0);         // c6
  CH(2, 1,1,1, 1,  1, 0, 131072+128,            0, 0, 0);         // c7
  CH(2, 0,0,0, 2,  1, 1, 524288+128,            1, 1, 192);       // c8
  CH(6, 0,0,1, 0,  1, 2, 524288+131072+128,     0, 0, 0);         // c9
  CH(6, 0,1,0, 1,  1, 0, 192,                   0, 0, 0);         // c10
  CH(2, 0,1,1, 2,  1, 1, 131072+192,            0, 0, 0);         // c11
  CH(2, 1,0,0, 0,  1, 2, 524288+192,            1, 0, 256);       // c12
  CH(6, 1,0,1, 1,  1, 0, 524288+131072+192,     0, 0, 0);         // c13
  CH(6, 1,1,0, 2,  1, 1, 256,                   0, 0, 0);         // c14
  CH(2, 1,1,1, 0,  1, 2, 131072+256,            0, 0, 0);         // c15
  CH(2, 0,0,0, 1,  1, 0, 524288+256,            1, 1, 320);       // c16
  CH(6, 0,0,1, 2,  1, 1, 524288+131072+256,     0, 0, 0);         // c17
  CH(6, 0,1,0, 0,  1, 2, 320,                   0, 0, 0);         // c18
  CH(2, 0,1,1, 1,  1, 0, 131072+320,            0, 0, 0);         // c19
  CH(2, 1,0,0, 2,  1, 1, 524288+320,            1, 0, 384);       // c20
  CH(6, 1,0,1, 0,  1, 2, 524288+131072+320,     0, 0, 0);         // c21
  CH(6, 1,1,0, 1,  1, 0, 384,                   0, 0, 0);         // c22
  CH(2, 1,1,1, 2,  1, 1, 131072+384,            0, 0, 0);         // c23
  CH(2, 0,0,0, 0,  1, 2, 524288+384,            1, 1, 448);       // c24
  CH(6, 0,0,1, 1,  1, 0, 524288+131072+384,     0, 0, 0);         // c25
  CH(6, 0,1,0, 2,  1, 1, 448,                   0, 0, 0);         // c26
  CH(2, 0,1,1, 0,  1, 2, 131072+448,            0, 0, 0);         // c27
  CH(2, 1,0,0, 1,  1, 0, 524288+448,            0, 0, 0);         // c28
  CH(2, 1,0,1, 2,  1, 1, 524288+131072+448,     0, 0, 0);         // c29
  CH(2, 1,1,0, 0,  0, 0, 0,                     0, 0, 0);         // c30
  CH(0, 1,1,1, 1,  0, 0, 0,                     0, 0, 0);         // c31

#undef SB
#undef BAR
#undef VMW
#undef LGK
#undef DSR
#undef STG_B
#undef STG_A
#undef MFMA16
#undef CH

  // ---------------- epilogue ----------------
  float scale = powf(sqrtf(128.f) / log1pf(128.f), alpha[0]);
  float kq[4], bi[4];
  #pragma unroll
  for (int nt = 0; nt < 4; ++nt) {
    int n = coh*64 + nt*16 + l15;
    kq[nt] = ksq[n]; bi[nt] = bias[n];
  }
  int oy = 2*(2*u2 + rp) + py;
  size_t orow = ((size_t)b*128 + oy) * 128 * COUT;
  #pragma unroll
  for (int mt = 0; mt < 4; ++mt) {
    #pragma unroll
    for (int r = 0; r < 4; ++r) {
      int v = mt*16 + l4*4 + r;
      int vpx = v + px;
      float ps = srow[rp*66 + vpx] + srow[rp*66 + vpx + 1]
               + srow[rp*66 + 66 + vpx] + srow[rp*66 + 66 + vpx + 1];
      #pragma unroll
      for (int nt = 0; nt < 4; ++nt) {
        float dot = acc[mt][nt][r];
        float dist = ps + kq[nt] - 2.f*dot + 1e-5f;
        float y = (dot*dot/dist + bi[nt]) * scale;
        int n = coh*64 + nt*16 + l15;
        out[orow + (size_t)(2*v + px)*COUT + n] = y;
      }
    }
  }
}

// ---------------- fallback (tiny ws): direct fp32 ----------------
__global__ __launch_bounds__(256) void fb_ksq(const float* __restrict__ w,
                                              float* __restrict__ ksq) {
  __shared__ float red[256];
  int co = blockIdx.x, t = threadIdx.x;
  float s = 0.f;
  for (int j = t; j < 4096; j += 256) { float v = w[(size_t)j*COUT + co]; s += v*v; }
  red[t] = s; __syncthreads();
  for (int off = 128; off > 0; off >>= 1) {
    if (t < off) red[t] += red[t + off];
    __syncthreads();
  }
  if (t == 0) ksq[co] = red[0];
}

__global__ __launch_bounds__(256) void fb_main(
    const float* __restrict__ x, const float* __restrict__ w,
    const float* __restrict__ bias, const float* __restrict__ alpha,
    const float* __restrict__ ksq, float* __restrict__ out)
{
  size_t idx = (size_t)blockIdx.x * 256 + threadIdx.x;
  int co = (int)(idx & 127);
  int ox = (int)((idx >> 7) & 127);
  int oy = (int)((idx >> 14) & 127);
  int b  = (int)(idx >> 21);
  int py = oy & 1, px = ox & 1, u = oy >> 1, v = ox >> 1;
  float dot = 0.f, ps = 0.f;
  for (int a = 0; a < 2; ++a) {
    int iy = u + py + a - 1;
    if (iy < 0 || iy > 63) continue;
    for (int b2 = 0; b2 < 2; ++b2) {
      int ix = v + px + b2 - 1;
      if (ix < 0 || ix > 63) continue;
      const float* xp = x + (((size_t)b*64 + iy)*64 + ix)*CIN;
      const float* wp = w + ((size_t)((py + 2*a)*4 + (px + 2*b2))*CIN)*COUT + co;
      for (int ci = 0; ci < CIN; ++ci) {
        float xv = xp[ci];
        dot += xv * wp[(size_t)ci*COUT];
        ps  += xv * xv;
      }
    }
  }
  float dist = ps + ksq[co] - 2.f*dot + 1e-5f;
  float scale = powf(sqrtf(128.f) / log1pf(128.f), alpha[0]);
  out[idx] = (dot*dot/dist + bias[co]) * scale;
}

// ---------------- launcher ----------------
extern "C" void kernel_launch(void* const* d_in, const int* in_sizes, int n_in,
                              void* d_out, int out_size, void* d_ws, size_t ws_size,
                              hipStream_t stream)
{
  const float* x     = (const float*)d_in[0];
  const float* w     = (const float*)d_in[1];
  const float* bias  = (const float*)d_in[2];
  const float* alpha = (const float*)d_in[3];
  float* out = (float*)d_out;

  if (ws_size < WS_NEEDED) {
    float* ksq = (float*)d_ws;
    fb_ksq<<<128, 256, 0, stream>>>(w, ksq);
    fb_main<<<131072, 256, 0, stream>>>(x, w, bias, alpha, ksq, out);
    return;
  }

  unsigned short* xpad = (unsigned short*)d_ws;
  unsigned short* wtp  = (unsigned short*)((char*)d_ws + WT_OFF);
  float* spad = (float*)((char*)d_ws + SPAD_OFF);
  float* ksq  = (float*)((char*)d_ws + KSQ_OFF);

  prep_all<<<17680, 256, 0, stream>>>(x, w, xpad, wtp, spad, ksq);
  yat_main<<<2048, 256, 0, stream>>>(xpad, wtp, spad, ksq, bias, alpha, out);
}

// Round 18
// 97.753 us; speedup vs baseline: 1.2252x; 1.0541x over previous
//
#include <hip/hip_runtime.h>
#include <cstdint>
#include <cstddef>

#define CIN   256
#define COUT  128

typedef float  f32x4  __attribute__((ext_vector_type(4)));
typedef __bf16 bf16x8 __attribute__((ext_vector_type(8)));
typedef unsigned int u32x4 __attribute__((ext_vector_type(4)));

// ---------------- workspace layout (bytes) ----------------
#define XPAD_BYTES (16ull*66*66*256*2)          // 35,684,352  bf16 padded x
#define WT_OFF     XPAD_BYTES
#define WT_BYTES   (16ull*128*256*2)            // 1,048,576   bf16 w, [tap][co][ci]
#define SPAD_OFF   (WT_OFF + WT_BYTES)
#define SPAD_BYTES (16ull*66*66*4)              // 278,784     fp32 per-pixel sum(x^2)
#define KSQ_OFF    (SPAD_OFF + SPAD_BYTES)
#define WS_NEEDED  (KSQ_OFF + 512)

__device__ __forceinline__ unsigned short f2bf(float f) {
  unsigned int u = __float_as_uint(f);
  u += 0x7fffu + ((u >> 16) & 1u);              // RNE
  return (unsigned short)(u >> 16);
}

__device__ __forceinline__ void async16(const void* lds, const void* g) {
  __builtin_amdgcn_global_load_lds(
      (const __attribute__((address_space(1))) unsigned int*)g,
      (__attribute__((address_space(3))) unsigned int*)lds, 16, 0, 0);
}

// ---------------- fused prep: pad x + spad | wt transpose | ksq ----------
__global__ __launch_bounds__(256) void prep_all(
    const float* __restrict__ x, const float* __restrict__ w,
    unsigned short* __restrict__ xpad, unsigned short* __restrict__ wt,
    float* __restrict__ spad, float* __restrict__ ksq)
{
  __shared__ __align__(16) unsigned short lw[32*128];
  __shared__ float red[256];
  int blk = blockIdx.x;
  int t = threadIdx.x;

  if (blk < 17424) {
    int wave = t >> 6, lane = t & 63;
    int p = blk * 4 + wave;
    int b = p / 4356;
    int rem = p - b * 4356;
    int iyp = rem / 66, ixp = rem - iyp * 66;
    bool interior = (iyp >= 1 && iyp <= 64 && ixp >= 1 && ixp <= 64);
    f32x4 v = {0.f, 0.f, 0.f, 0.f};
    if (interior) {
      const float* src = x + (((size_t)b*64 + (iyp-1))*64 + (ixp-1))*CIN + lane*4;
      v = *(const f32x4*)src;
    }
    ushort4 h;
    h.x = f2bf(v.x); h.y = f2bf(v.y); h.z = f2bf(v.z); h.w = f2bf(v.w);
    *(ushort4*)(xpad + (size_t)p*CIN + lane*4) = h;
    float s = v.x*v.x + v.y*v.y + v.z*v.z + v.w*v.w;
    #pragma unroll
    for (int off = 32; off > 0; off >>= 1) s += __shfl_down(s, off);
    if (lane == 0) spad[p] = s;
  } else if (blk < 17552) {
    int pblk = blk - 17424;
    int tap = pblk >> 3;
    int ci0 = (pblk & 7) * 32;
    int co4 = (t & 31) * 4;
    #pragma unroll
    for (int i = 0; i < 4; ++i) {
      int ci = (t >> 5) + i*8;
      const float* src = w + ((size_t)(tap*256 + ci0 + ci))*COUT + co4;
      f32x4 v = *(const f32x4*)src;
      ushort4 h; h.x = f2bf(v.x); h.y = f2bf(v.y); h.z = f2bf(v.z); h.w = f2bf(v.w);
      *(ushort4*)&lw[ci*128 + co4] = h;
    }
    __syncthreads();
    int co = t >> 1, h16 = (t & 1) * 16;
    union { unsigned short u[16]; uint4 q[2]; } tmp;
    #pragma unroll
    for (int i = 0; i < 16; ++i) tmp.u[i] = lw[(h16 + i)*128 + co];
    uint4* dst = (uint4*)(wt + ((size_t)tap*128 + co)*CIN + ci0 + h16);
    dst[0] = tmp.q[0]; dst[1] = tmp.q[1];
  } else {
    int co = blk - 17552;
    float s = 0.f;
    for (int j = t; j < 4096; j += 256) { float v = w[(size_t)j*COUT + co]; s += v*v; }
    red[t] = s; __syncthreads();
    for (int off = 128; off > 0; off >>= 1) {
      if (t < off) red[t] += red[t + off];
      __syncthreads();
    }
    if (t == 0) ksq[co] = red[0];
  }
}

// ---------------- main fused kernel (64x128 wave tile, 2 blocks/CU) -------
// grid = 1024: bid -> px=bid&1, py=(bid>>1)&1, u4=(bid>>2)&15, b=bid>>6
// block = 256 (4 waves): wave rp = u-row; wave tile 64 v x 128 co (full N).
// reads/MFMA = 12/32 = 0.375 (was 0.5) -> per-CU LDS ~74k cyc ~= MFMA 79.5k.
// A: [5 rows][66 col][32 ci], depth-2, 22528 B stride (padded for round-5
//    overrun; R14-proven scrap-clamped staging map, 6 async16/wave).
// B: [128 co][32 ci], depth-3 (8192 B). Swizzle f(col)=(col>>1)&3 (R17, 0-cf).
// 32 chunks: c -> s=c>>2, a=(c>>1)&1, bb=c&1. Stage dist: B +2, A +4.
// FIFO VMW {2,8,8,2}x7 + {2,2,2,0} (A-stage=6 -> forced-retire keep=8).
__global__ __launch_bounds__(256, 2) void yat_main(
    const unsigned short* __restrict__ xpad,
    const unsigned short* __restrict__ wt,
    const float* __restrict__ spad,
    const float* __restrict__ ksq,
    const float* __restrict__ bias,
    const float* __restrict__ alpha,
    float* __restrict__ out)
{
  __shared__ __align__(16) unsigned short xsA[2][11264];  // 2 x 22528 B (padded)
  __shared__ __align__(16) unsigned short xsB[3][4096];   // 3 x 8192 B
  __shared__ __align__(16) unsigned short scrap[512];     // 1 KB dump
  __shared__ float srow[330];

  int orig = blockIdx.x;
  int bid = (orig & 7) * 128 + (orig >> 3);               // XCD-contiguous
  int px = bid & 1, py = (bid >> 1) & 1, u4 = (bid >> 2) & 15, b = bid >> 6;
  int t = threadIdx.x, wave = t >> 6, lane = t & 63;
  int rp = wave;                                          // u-row 0..3
  int l15 = lane & 15, l4 = lane >> 4;
  int bRow0 = u4*4 + py;

  for (int i = t; i < 330; i += 256) {
    int r = i / 66, c = i - r*66;
    srow[i] = spad[((size_t)b*66 + bRow0 + r)*66 + c];
  }
  asm volatile("s_waitcnt vmcnt(0) lgkmcnt(0)" ::: "memory");

  // ---- A staging: 1320 valid segs (5 rows x 66 col x 4 q); 6 rounds ----
  const char* srcA[6];
  unsigned short* dstA[6];
  int mulA[6];
  {
    #pragma unroll
    for (int r = 0; r < 5; ++r) {
      int seg = r*256 + t;
      int row = seg / 264; int r2 = seg - row*264;
      int col = r2 >> 2, q = r2 & 3;
      srcA[r] = (const char*)xpad
              + (((size_t)(b*66 + bRow0 + row))*66 + col)*512
              + ((q ^ ((col>>1)&3))*16);
      dstA[r] = &xsA[0][0] + (size_t)(r*2048 + wave*512);
      mulA[r] = 11264;
    }
    int seg = 1280 + t; if (seg > 1319) seg = 1319;       // clamp (dup content)
    int row = seg / 264; int r2 = seg - row*264;
    int col = r2 >> 2, q = r2 & 3;
    srcA[5] = (const char*)xpad
            + (((size_t)(b*66 + bRow0 + row))*66 + col)*512
            + ((q ^ ((col>>1)&3))*16);
    dstA[5] = (wave == 0) ? (&xsA[0][0] + 10240) : &scrap[0];
    mulA[5] = (wave == 0) ? 11264 : 0;
  }
  // ---- B staging: 512 segs; 2 rounds x 4 waves ----
  const char* srcB[2];
  unsigned short* dstB[2];
  {
    int baseTap = py*4 + px;
    #pragma unroll
    for (int r = 0; r < 2; ++r) {
      int seg = r*256 + t;
      int co = seg >> 2, qd = seg & 3;
      srcB[r] = (const char*)wt + (size_t)baseTap*65536
              + (size_t)co*512 + ((qd ^ ((co>>1)&3))*16);
      dstB[r] = &xsB[0][0] + (size_t)(r*2048 + wave*512);
    }
  }

  // ---- per-lane ds_read bases (swizzled, f = (col>>1)&3) ----
  unsigned abA[2];
  #pragma unroll
  for (int bb = 0; bb < 2; ++bb) {
    int c0 = l15 + px + bb;
    abA[bb] = (unsigned)(size_t)(&xsA[0][0])
            + (unsigned)(rp*4224 + c0*64 + ((l4 ^ ((c0>>1)&3)) << 4));
  }
  unsigned abB = (unsigned)(size_t)(&xsB[0][0])
               + (unsigned)(l15*64 + ((l4 ^ ((l15>>1)&3)) << 4));

  f32x4 acc[4][8];
  #pragma unroll
  for (int i = 0; i < 4; ++i)
    #pragma unroll
    for (int j = 0; j < 8; ++j)
      acc[i][j] = (f32x4){0.f, 0.f, 0.f, 0.f};

  u32x4 Af[4], Bf[8];

#define SB  __builtin_amdgcn_sched_barrier(0)
#define BAR __builtin_amdgcn_s_barrier()
#define VMW(N) do { asm volatile("s_waitcnt vmcnt(" #N ")" ::: "memory"); SB; } while (0)
#define LGK(N) do { asm volatile("s_waitcnt lgkmcnt(" #N ")" ::: "memory"); SB; } while (0)
#define DSR(dst, addr, off)                                                \
  asm volatile("ds_read_b128 %0, %1 offset:%c2"                            \
               : "=v"(dst) : "v"(addr), "i"(off))

#define STG_B(BI2, OFF) {                                                  \
    async16(dstB[0] + (size_t)(BI2)*4096, srcB[0] + (OFF));                \
    async16(dstB[1] + (size_t)(BI2)*4096, srcB[1] + (OFF)); }
#define STG_A(BUF2, OFF) {                                                 \
    async16(dstA[0] + (size_t)(BUF2)*mulA[0], srcA[0] + (OFF));            \
    async16(dstA[1] + (size_t)(BUF2)*mulA[1], srcA[1] + (OFF));            \
    async16(dstA[2] + (size_t)(BUF2)*mulA[2], srcA[2] + (OFF));            \
    async16(dstA[3] + (size_t)(BUF2)*mulA[3], srcA[3] + (OFF));            \
    async16(dstA[4] + (size_t)(BUF2)*mulA[4], srcA[4] + (OFF));            \
    async16(dstA[5] + (size_t)(BUF2)*mulA[5], srcA[5] + (OFF)); }

#define MFMA_H(NT0) {                                                      \
    _Pragma("unroll")                                                      \
    for (int mt = 0; mt < 4; ++mt)                                         \
      _Pragma("unroll")                                                    \
      for (int nt = NT0; nt < NT0 + 4; ++nt)                               \
        acc[mt][nt] = __builtin_amdgcn_mfma_f32_16x16x32_bf16(             \
            __builtin_bit_cast(bf16x8, Af[mt]),                            \
            __builtin_bit_cast(bf16x8, Bf[nt]),                            \
            acc[mt][nt], 0, 0, 0); }

  // chunk: VMW(N), barrier, 12 reads (A4 + B8), stages, split-lgk MFMA 32
#define CH(N, BUFA, AA, BB, BI, DOB, BI2, OFFB, DOA, BUFA2, OFFA) {        \
    VMW(N); BAR;                                                           \
    DSR(Af[0], abA[BB], (BUFA)*22528 + (AA)*4224 + 0);                     \
    DSR(Af[1], abA[BB], (BUFA)*22528 + (AA)*4224 + 1024);                  \
    DSR(Af[2], abA[BB], (BUFA)*22528 + (AA)*4224 + 2048);                  \
    DSR(Af[3], abA[BB], (BUFA)*22528 + (AA)*4224 + 3072);                  \
    DSR(Bf[0], abB, (BI)*8192 + 0);                                        \
    DSR(Bf[1], abB, (BI)*8192 + 1024);                                     \
    DSR(Bf[2], abB, (BI)*8192 + 2048);                                     \
    DSR(Bf[3], abB, (BI)*8192 + 3072);                                     \
    DSR(Bf[4], abB, (BI)*8192 + 4096);                                     \
    DSR(Bf[5], abB, (BI)*8192 + 5120);                                     \
    DSR(Bf[6], abB, (BI)*8192 + 6144);                                     \
    DSR(Bf[7], abB, (BI)*8192 + 7168);                                     \
    SB;                                                                    \
    if (DOB) STG_B(BI2, OFFB);                                             \
    if (DOA) STG_A(BUFA2, OFFA);                                           \
    SB;                                                                    \
    LGK(4);                                                                \
    __builtin_amdgcn_s_setprio(1); MFMA_H(0);                              \
    LGK(0);                                                                \
    MFMA_H(4); __builtin_amdgcn_s_setprio(0); SB; }

  SB;
  // ---- prologue: B(c0)->BI0, A(s0)->buf0, B(c1)->BI1 ----
  STG_B(0, 0);
  STG_A(0, 0);
  STG_B(1, 131072);
  SB;

  //  N  bufA a bb BI | B2? BI2 OFFB                  | A2? buf2 OFFA
  CH(2, 0,0,0, 0,  1, 2, 524288,                1, 1, 64);        // c0
  CH(8, 0,0,1, 1,  1, 0, 524288+131072,         0, 0, 0);         // c1
  CH(8, 0,1,0, 2,  1, 1, 64,                    0, 0, 0);         // c2
  CH(2, 0,1,1, 0,  1, 2, 131072+64,             0, 0, 0);         // c3
  CH(2, 1,0,0, 1,  1, 0, 524288+64,             1, 0, 128);       // c4
  CH(8, 1,0,1, 2,  1, 1, 524288+131072+64,      0, 0, 0);         // c5
  CH(8, 1,1,0, 0,  1, 2, 128,                   0, 0, 0);         // c6
  CH(2, 1,1,1, 1,  1, 0, 131072+128,            0, 0, 0);         // c7
  CH(2, 0,0,0, 2,  1, 1, 524288+128,            1, 1, 192);       // c8
  CH(8, 0,0,1, 0,  1, 2, 524288+131072+128,     0, 0, 0);         // c9
  CH(8, 0,1,0, 1,  1, 0, 192,                   0, 0, 0);         // c10
  CH(2, 0,1,1, 2,  1, 1, 131072+192,            0, 0, 0);         // c11
  CH(2, 1,0,0, 0,  1, 2, 524288+192,            1, 0, 256);       // c12
  CH(8, 1,0,1, 1,  1, 0, 524288+131072+192,     0, 0, 0);         // c13
  CH(8, 1,1,0, 2,  1, 1, 256,                   0, 0, 0);         // c14
  CH(2, 1,1,1, 0,  1, 2, 131072+256,            0, 0, 0);         // c15
  CH(2, 0,0,0, 1,  1, 0, 524288+256,            1, 1, 320);       // c16
  CH(8, 0,0,1, 2,  1, 1, 524288+131072+256,     0, 0, 0);         // c17
  CH(8, 0,1,0, 0,  1, 2, 320,                   0, 0, 0);         // c18
  CH(2, 0,1,1, 1,  1, 0, 131072+320,            0, 0, 0);         // c19
  CH(2, 1,0,0, 2,  1, 1, 524288+320,            1, 0, 384);       // c20
  CH(8, 1,0,1, 0,  1, 2, 524288+131072+320,     0, 0, 0);         // c21
  CH(8, 1,1,0, 1,  1, 0, 384,                   0, 0, 0);         // c22
  CH(2, 1,1,1, 2,  1, 1, 131072+384,            0, 0, 0);         // c23
  CH(2, 0,0,0, 0,  1, 2, 524288+384,            1, 1, 448);       // c24
  CH(8, 0,0,1, 1,  1, 0, 524288+131072+384,     0, 0, 0);         // c25
  CH(8, 0,1,0, 2,  1, 1, 448,                   0, 0, 0);         // c26
  CH(2, 0,1,1, 0,  1, 2, 131072+448,            0, 0, 0);         // c27
  CH(2, 1,0,0, 1,  1, 0, 524288+448,            0, 0, 0);         // c28
  CH(2, 1,0,1, 2,  1, 1, 524288+131072+448,     0, 0, 0);         // c29
  CH(2, 1,1,0, 0,  0, 0, 0,                     0, 0, 0);         // c30
  CH(0, 1,1,1, 1,  0, 0, 0,                     0, 0, 0);         // c31

#undef SB
#undef BAR
#undef VMW
#undef LGK
#undef DSR
#undef STG_B
#undef STG_A
#undef MFMA_H
#undef CH

  // ---------------- epilogue ----------------
  float scale = powf(sqrtf(128.f) / log1pf(128.f), alpha[0]);
  float kq[8], bi[8];
  #pragma unroll
  for (int nt = 0; nt < 8; ++nt) {
    int n = nt*16 + l15;
    kq[nt] = ksq[n]; bi[nt] = bias[n];
  }
  int oy = 2*(u4*4 + rp) + py;
  size_t orow = ((size_t)b*128 + oy) * 128 * COUT;
  #pragma unroll
  for (int mt = 0; mt < 4; ++mt) {
    #pragma unroll
    for (int r = 0; r < 4; ++r) {
      int v = mt*16 + l4*4 + r;
      int vpx = v + px;
      float ps = srow[rp*66 + vpx] + srow[rp*66 + vpx + 1]
               + srow[rp*66 + 66 + vpx] + srow[rp*66 + 66 + vpx + 1];
      #pragma unroll
      for (int nt = 0; nt < 8; ++nt) {
        float dot = acc[mt][nt][r];
        float dist = ps + kq[nt] - 2.f*dot + 1e-5f;
        float y = (dot*dot/dist + bi[nt]) * scale;
        int n = nt*16 + l15;
        out[orow + (size_t)(2*v + px)*COUT + n] = y;
      }
    }
  }
}

// ---------------- fallback (tiny ws): direct fp32 ----------------
__global__ __launch_bounds__(256) void fb_ksq(const float* __restrict__ w,
                                              float* __restrict__ ksq) {
  __shared__ float red[256];
  int co = blockIdx.x, t = threadIdx.x;
  float s = 0.f;
  for (int j = t; j < 4096; j += 256) { float v = w[(size_t)j*COUT + co]; s += v*v; }
  red[t] = s; __syncthreads();
  for (int off = 128; off > 0; off >>= 1) {
    if (t < off) red[t] += red[t + off];
    __syncthreads();
  }
  if (t == 0) ksq[co] = red[0];
}

__global__ __launch_bounds__(256) void fb_main(
    const float* __restrict__ x, const float* __restrict__ w,
    const float* __restrict__ bias, const float* __restrict__ alpha,
    const float* __restrict__ ksq, float* __restrict__ out)
{
  size_t idx = (size_t)blockIdx.x * 256 + threadIdx.x;
  int co = (int)(idx & 127);
  int ox = (int)((idx >> 7) & 127);
  int oy = (int)((idx >> 14) & 127);
  int b  = (int)(idx >> 21);
  int py = oy & 1, px = ox & 1, u = oy >> 1, v = ox >> 1;
  float dot = 0.f, ps = 0.f;
  for (int a = 0; a < 2; ++a) {
    int iy = u + py + a - 1;
    if (iy < 0 || iy > 63) continue;
    for (int b2 = 0; b2 < 2; ++b2) {
      int ix = v + px + b2 - 1;
      if (ix < 0 || ix > 63) continue;
      const float* xp = x + (((size_t)b*64 + iy)*64 + ix)*CIN;
      const float* wp = w + ((size_t)((py + 2*a)*4 + (px + 2*b2))*CIN)*COUT + co;
      for (int ci = 0; ci < CIN; ++ci) {
        float xv = xp[ci];
        dot += xv * wp[(size_t)ci*COUT];
        ps  += xv * xv;
      }
    }
  }
  float dist = ps + ksq[co] - 2.f*dot + 1e-5f;
  float scale = powf(sqrtf(128.f) / log1pf(128.f), alpha[0]);
  out[idx] = (dot*dot/dist + bias[co]) * scale;
}

// ---------------- launcher ----------------
extern "C" void kernel_launch(void* const* d_in, const int* in_sizes, int n_in,
                              void* d_out, int out_size, void* d_ws, size_t ws_size,
                              hipStream_t stream)
{
  const float* x     = (const float*)d_in[0];
  const float* w     = (const float*)d_in[1];
  const float* bias  = (const float*)d_in[2];
  const float* alpha = (const float*)d_in[3];
  float* out = (float*)d_out;

  if (ws_size < WS_NEEDED) {
    float* ksq = (float*)d_ws;
    fb_ksq<<<128, 256, 0, stream>>>(w, ksq);
    fb_main<<<131072, 256, 0, stream>>>(x, w, bias, alpha, ksq, out);
    return;
  }

  unsigned short* xpad = (unsigned short*)d_ws;
  unsigned short* wtp  = (unsigned short*)((char*)d_ws + WT_OFF);
  float* spad = (float*)((char*)d_ws + SPAD_OFF);
  float* ksq  = (float*)((char*)d_ws + KSQ_OFF);

  prep_all<<<17680, 256, 0, stream>>>(x, w, xpad, wtp, spad, ksq);
  yat_main<<<1024, 256, 0, stream>>>(xpad, wtp, spad, ksq, bias, alpha, out);
}